// Round 12
// baseline (157.415 us; speedup 1.0000x reference)
//
#include <hip/hip_runtime.h>
#include <hip/hip_bf16.h>

// MDTA (multi-head cross attention with l2-normed q/k) for MI355X.
// B=8, N=4096, Ktok=256, C=512, H=8, D=64. Inputs f32, output f32.
//
// R8 187.9 -> R9 153.1 -> R10 167.8 -> R11 151.2.
// R11 evidence: reg-staged-f32-A GEMM is latency-bound (65us, HBM 15%);
// gload_lds GEMM (out_gemm) hits 4.4 TB/s. R12: hoist f32->bf16 conversion
// of X,S into the cvt pass (Xb/Sb scratch in d_out, dead before out_gemm
// overwrites); proj becomes a pure gload_lds dbuf GEMM like out_gemm.
//
// Pipeline: cvt_all (W,X,S -> bf16) -> proj_all (Q,Kn,Vt) -> attn_fused
//           -> out_gemm (residual f32).

typedef __bf16 bf16;
typedef __attribute__((ext_vector_type(8))) __bf16 bf16x8;
typedef __attribute__((ext_vector_type(4))) float f32x4;

__device__ __forceinline__ void gload_lds16(const void* g, void* l) {
  __builtin_amdgcn_global_load_lds(
      (__attribute__((address_space(1))) void*)g,
      (__attribute__((address_space(3))) void*)l, 16, 0, 0);
}

__device__ __forceinline__ unsigned pack2(float a, float b) {
  unsigned short x = __builtin_bit_cast(unsigned short, (bf16)a);
  unsigned short y = __builtin_bit_cast(unsigned short, (bf16)b);
  return (unsigned)x | ((unsigned)y << 16);
}

// ---------------------------------------------------------------------------
// Convert X (2097152 chunks), S (131072), Wq/Wk/Wv/Wo (32768 each) to bf16.
// One chunk = 8 f32 -> 8 bf16 (16B store). Grid 9216 x 256.
// ---------------------------------------------------------------------------
__global__ __launch_bounds__(256) void cvt_all(
    const float* __restrict__ X, const float* __restrict__ S,
    const float* __restrict__ Wq, const float* __restrict__ Wk,
    const float* __restrict__ Wv, const float* __restrict__ Wo,
    bf16* __restrict__ Xb, bf16* __restrict__ Sb, bf16* __restrict__ Wqb,
    bf16* __restrict__ Wkb, bf16* __restrict__ Wvb, bf16* __restrict__ Wob) {
  int i = blockIdx.x * 256 + threadIdx.x;
  const float* src;
  bf16* dst;
  int r;
  if (i < 2097152) {
    src = X; dst = Xb; r = i;
  } else if (i < 2228224) {
    src = S; dst = Sb; r = i - 2097152;
  } else {
    int j = i - 2228224;
    int w = j >> 15;
    r = j & 32767;
    src = (w == 0) ? Wq : (w == 1) ? Wk : (w == 2) ? Wv : Wo;
    dst = (w == 0) ? Wqb : (w == 1) ? Wkb : (w == 2) ? Wvb : Wob;
  }
  float4 a = *(const float4*)(src + (size_t)r * 8);
  float4 b = *(const float4*)(src + (size_t)r * 8 + 4);
  uint4 v;
  v.x = pack2(a.x, a.y);
  v.y = pack2(a.z, a.w);
  v.z = pack2(b.x, b.y);
  v.w = pack2(b.z, b.w);
  *(uint4*)(dst + (size_t)r * 8) = v;
}

// ---------------------------------------------------------------------------
// Fused Q/K/V projection, all-bf16 operands. Exact out_gemm structure:
// 128x128 tile, BK=32, 16 iters, 2-phase gload_lds double-buffer (32 KB LDS,
// ~4 blocks/CU), XCD swizzle. Epilogues: l2norm (Q,Kn) / transposed Vt.
// ---------------------------------------------------------------------------
__global__ __launch_bounds__(256) void proj_all(
    const bf16* __restrict__ Xb, const bf16* __restrict__ Sb,
    const bf16* __restrict__ Wqb, const bf16* __restrict__ Wkb,
    const bf16* __restrict__ Wvb, bf16* __restrict__ Q,
    bf16* __restrict__ Kn, bf16* __restrict__ Vt) {
  __shared__ __align__(16) bf16 As[2][128 * 32];
  __shared__ __align__(16) bf16 Bs[2][128 * 32];

  // 1152 = 8 XCDs x 144; consecutive lg (4 n-tiles of an A panel) share XCD.
  const int lg = (blockIdx.x & 7) * 144 + (blockIdx.x >> 3);

  const bf16* A;
  const bf16* W;
  int m0, kind;  // 0=Q, 1=K, 2=V
  if (lg < 1024) {
    kind = 0; A = Xb; W = Wqb; m0 = (lg >> 2) * 128;
  } else if (lg < 1088) {
    kind = 1; A = Sb; W = Wkb; m0 = ((lg - 1024) >> 2) * 128;
  } else {
    kind = 2; A = Sb; W = Wvb; m0 = ((lg - 1088) >> 2) * 128;
  }
  const int n0 = (lg & 3) * 128;

  const int tid = threadIdx.x;
  const int wid = tid >> 6, lane = tid & 63;
  const int wr = wid >> 1, wc = wid & 1;
  const int g = lane >> 4, c16 = lane & 15;
  const int c0 = tid, c1 = 256 + tid;
  const int r0 = c0 >> 2, cc0 = c0 & 3;
  const int r1 = c1 >> 2, cc1 = c1 & 3;

  f32x4 acc[4][4] = {};

  gload_lds16(A + (size_t)(m0 + r0) * 512 + cc0 * 8, As[0] + (tid & ~63) * 8);
  gload_lds16(A + (size_t)(m0 + r1) * 512 + cc1 * 8,
              As[0] + (256 + (tid & ~63)) * 8);
  gload_lds16(W + (size_t)(n0 + r0) * 512 + cc0 * 8, Bs[0] + (tid & ~63) * 8);
  gload_lds16(W + (size_t)(n0 + r1) * 512 + cc1 * 8,
              Bs[0] + (256 + (tid & ~63)) * 8);
  __syncthreads();

  int cur = 0;
  for (int t = 0; t < 16; ++t) {
    const int kb = (t + 1) * 32;
    if (t < 15) {
      gload_lds16(A + (size_t)(m0 + r0) * 512 + kb + cc0 * 8,
                  As[cur ^ 1] + (tid & ~63) * 8);
      gload_lds16(A + (size_t)(m0 + r1) * 512 + kb + cc1 * 8,
                  As[cur ^ 1] + (256 + (tid & ~63)) * 8);
      gload_lds16(W + (size_t)(n0 + r0) * 512 + kb + cc0 * 8,
                  Bs[cur ^ 1] + (tid & ~63) * 8);
      gload_lds16(W + (size_t)(n0 + r1) * 512 + kb + cc1 * 8,
                  Bs[cur ^ 1] + (256 + (tid & ~63)) * 8);
    }
    bf16x8 af[4], bfr[4];
#pragma unroll
    for (int mi = 0; mi < 4; ++mi)
      af[mi] =
          *(const bf16x8*)(As[cur] + (wr * 64 + mi * 16 + c16) * 32 + g * 8);
#pragma unroll
    for (int ni = 0; ni < 4; ++ni)
      bfr[ni] =
          *(const bf16x8*)(Bs[cur] + (wc * 64 + ni * 16 + c16) * 32 + g * 8);
#pragma unroll
    for (int mi = 0; mi < 4; ++mi)
#pragma unroll
      for (int ni = 0; ni < 4; ++ni)
        acc[mi][ni] = __builtin_amdgcn_mfma_f32_16x16x32_bf16(
            af[mi], bfr[ni], acc[mi][ni], 0, 0, 0);
    __syncthreads();
    cur ^= 1;
  }

  // ---- epilogue. C/D frag: col = lane&15, row = (lane>>4)*4 + j   [m89]
  if (kind != 2) {
    bf16* C = (kind == 0) ? Q : Kn;
    // l2 norm over the wave's 64 cols (= exactly one head).
#pragma unroll
    for (int mi = 0; mi < 4; ++mi) {
      float ss[4];
#pragma unroll
      for (int j = 0; j < 4; ++j) {
        float s = 0.f;
#pragma unroll
        for (int ni = 0; ni < 4; ++ni) {
          float v = acc[mi][ni][j];
          s += v * v;
        }
        ss[j] = s;
      }
#pragma unroll
      for (int msk = 1; msk < 16; msk <<= 1)
#pragma unroll
        for (int j = 0; j < 4; ++j) ss[j] += __shfl_xor(ss[j], msk, 64);
      float inv[4];
#pragma unroll
      for (int j = 0; j < 4; ++j) inv[j] = rsqrtf(fmaxf(ss[j], 1e-24f));
#pragma unroll
      for (int ni = 0; ni < 4; ++ni)
#pragma unroll
        for (int j = 0; j < 4; ++j) {
          size_t idx = (size_t)(m0 + wr * 64 + mi * 16 + g * 4 + j) * 512 +
                       n0 + wc * 64 + ni * 16 + c16;
          C[idx] = (bf16)(acc[mi][ni][j] * inv[j]);
        }
    }
  } else {
    // transposed store into Vt[b][h][d][t] (M=2048): 4 j = 4 tokens -> 8B
#pragma unroll
    for (int mi = 0; mi < 4; ++mi) {
      int m = m0 + wr * 64 + mi * 16 + g * 4;  // +j
      int b = m >> 8, tt = m & 255;
#pragma unroll
      for (int ni = 0; ni < 4; ++ni) {
        int col = n0 + wc * 64 + ni * 16 + c16;
        int h = col >> 6, d = col & 63;
        uint2 v;
        v.x = pack2(acc[mi][ni][0], acc[mi][ni][1]);
        v.y = pack2(acc[mi][ni][2], acc[mi][ni][3]);
        *(uint2*)(Vt + ((size_t)((b * 8 + h) * 64 + d) * 256 + tt)) = v;
      }
    }
  }
}

// ---------------------------------------------------------------------------
// out = X + O @ Wo^T, f32 output. R9-proven: 128x128, BK=32, gload_lds dbuf.
// ---------------------------------------------------------------------------
__global__ __launch_bounds__(256) void out_gemm(
    const bf16* __restrict__ O, const bf16* __restrict__ Wob,
    const float* __restrict__ Xres, float* __restrict__ out) {
  __shared__ __align__(16) bf16 As[2][128 * 32];
  __shared__ __align__(16) bf16 Bs[2][128 * 32];

  const int lg = (blockIdx.x & 7) * 128 + (blockIdx.x >> 3);  // XCD swizzle
  const int m0 = (lg >> 2) * 128, n0 = (lg & 3) * 128;

  const int tid = threadIdx.x;
  const int wid = tid >> 6, lane = tid & 63;
  const int wr = wid >> 1, wc = wid & 1;
  const int g = lane >> 4, c16 = lane & 15;
  const int c0 = tid, c1 = 256 + tid;
  const int r0 = c0 >> 2, cc0 = c0 & 3;
  const int r1 = c1 >> 2, cc1 = c1 & 3;

  f32x4 acc[4][4] = {};

  gload_lds16(O + (size_t)(m0 + r0) * 512 + cc0 * 8, As[0] + (tid & ~63) * 8);
  gload_lds16(O + (size_t)(m0 + r1) * 512 + cc1 * 8,
              As[0] + (256 + (tid & ~63)) * 8);
  gload_lds16(Wob + (size_t)(n0 + r0) * 512 + cc0 * 8,
              Bs[0] + (tid & ~63) * 8);
  gload_lds16(Wob + (size_t)(n0 + r1) * 512 + cc1 * 8,
              Bs[0] + (256 + (tid & ~63)) * 8);
  __syncthreads();

  int cur = 0;
  for (int t = 0; t < 16; ++t) {
    const int kb = (t + 1) * 32;
    if (t < 15) {
      gload_lds16(O + (size_t)(m0 + r0) * 512 + kb + cc0 * 8,
                  As[cur ^ 1] + (tid & ~63) * 8);
      gload_lds16(O + (size_t)(m0 + r1) * 512 + kb + cc1 * 8,
                  As[cur ^ 1] + (256 + (tid & ~63)) * 8);
      gload_lds16(Wob + (size_t)(n0 + r0) * 512 + kb + cc0 * 8,
                  Bs[cur ^ 1] + (tid & ~63) * 8);
      gload_lds16(Wob + (size_t)(n0 + r1) * 512 + kb + cc1 * 8,
                  Bs[cur ^ 1] + (256 + (tid & ~63)) * 8);
    }
    bf16x8 af[4], bfr[4];
#pragma unroll
    for (int mi = 0; mi < 4; ++mi)
      af[mi] =
          *(const bf16x8*)(As[cur] + (wr * 64 + mi * 16 + c16) * 32 + g * 8);
#pragma unroll
    for (int ni = 0; ni < 4; ++ni)
      bfr[ni] =
          *(const bf16x8*)(Bs[cur] + (wc * 64 + ni * 16 + c16) * 32 + g * 8);
#pragma unroll
    for (int mi = 0; mi < 4; ++mi)
#pragma unroll
      for (int ni = 0; ni < 4; ++ni)
        acc[mi][ni] = __builtin_amdgcn_mfma_f32_16x16x32_bf16(
            af[mi], bfr[ni], acc[mi][ni], 0, 0, 0);
    __syncthreads();
    cur ^= 1;
  }

#pragma unroll
  for (int mi = 0; mi < 4; ++mi)
#pragma unroll
    for (int ni = 0; ni < 4; ++ni)
#pragma unroll
      for (int j = 0; j < 4; ++j) {
        size_t idx = (size_t)(m0 + wr * 64 + mi * 16 + g * 4 + j) * 512 + n0 +
                     wc * 64 + ni * 16 + c16;
        out[idx] = acc[mi][ni][j] + Xres[idx];
      }
}

// ---------------------------------------------------------------------------
// Fused attention (unchanged, proven). Block = (b,h,128 q), 512 thr.
// ---------------------------------------------------------------------------
__global__ __launch_bounds__(512) void attn_fused(
    const bf16* __restrict__ Qn, const bf16* __restrict__ Kn,
    const bf16* __restrict__ Vt, const float* __restrict__ temp,
    bf16* __restrict__ O) {
  __shared__ __align__(16) char smem[147456];
  // [0,32768) Ksm [256t][64d] | [32768,65536) Vsm [64d][256t]
  // [65536,81920) Qsm [128q][64d] | [81920,147456) Psm [128q][256k]

  const int tid = threadIdx.x;
  const int w = tid >> 6, lane = tid & 63;
  const int g = lane >> 4, c16 = lane & 15;
  const int bx = blockIdx.x;
  const int nt = bx & 31, h = (bx >> 5) & 7, b = bx >> 8;
  const int n0 = nt * 128;

  {
    const bf16* Ksrc = Kn + ((size_t)b * 256) * 512 + h * 64;
#pragma unroll
    for (int it = 0; it < 4; ++it) {
      int c = it * 512 + tid;
      int t = c >> 3, dc = c & 7;
      int4 v = *(const int4*)(Ksrc + (size_t)t * 512 + dc * 8);
      int off = (t * 128 + dc * 16) ^ ((t & 7) << 4);
      *(int4*)(smem + off) = v;
    }
    const bf16* Vsrc = Vt + (size_t)((b * 8 + h) * 64) * 256;
#pragma unroll
    for (int it = 0; it < 4; ++it) {
      int c = it * 512 + tid;
      int d = c >> 5, tc = c & 31;
      int4 v = *(const int4*)(Vsrc + (size_t)d * 256 + tc * 8);
      int off = (d * 512 + tc * 16) ^ ((d & 7) << 4);
      *(int4*)(smem + 32768 + off) = v;
    }
    const bf16* Qsrc = Qn + ((size_t)b * 4096 + n0) * 512 + h * 64;
#pragma unroll
    for (int it = 0; it < 2; ++it) {
      int c = it * 512 + tid;
      int q = c >> 3, dc = c & 7;
      int4 v = *(const int4*)(Qsrc + (size_t)q * 512 + dc * 8);
      int off = (q * 128 + dc * 16) ^ ((q & 7) << 4);
      *(int4*)(smem + 65536 + off) = v;
    }
  }
  __syncthreads();

  const int q = w * 16 + c16;

  f32x4 sacc[16] = {};
  bf16x8 qf[2];
#pragma unroll
  for (int s = 0; s < 2; ++s) {
    int off = (q * 128 + s * 64 + g * 16) ^ ((q & 7) << 4);
    qf[s] = *(const bf16x8*)(smem + 65536 + off);
  }
#pragma unroll
  for (int mi = 0; mi < 16; ++mi) {
#pragma unroll
    for (int s = 0; s < 2; ++s) {
      int t = mi * 16 + c16;
      int off = (t * 128 + s * 64 + g * 16) ^ ((t & 7) << 4);
      bf16x8 kf = *(const bf16x8*)(smem + off);
      sacc[mi] = __builtin_amdgcn_mfma_f32_16x16x32_bf16(kf, qf[s], sacc[mi],
                                                         0, 0, 0);
    }
  }

  float tv = temp[h];
  float mx = -1e30f;
#pragma unroll
  for (int mi = 0; mi < 16; ++mi)
#pragma unroll
    for (int j = 0; j < 4; ++j) {
      sacc[mi][j] *= tv;
      mx = fmaxf(mx, sacc[mi][j]);
    }
  mx = fmaxf(mx, __shfl_xor(mx, 16, 64));
  mx = fmaxf(mx, __shfl_xor(mx, 32, 64));
  float sum = 0.f;
#pragma unroll
  for (int mi = 0; mi < 16; ++mi)
#pragma unroll
    for (int j = 0; j < 4; ++j) {
      float p = __expf(sacc[mi][j] - mx);
      sacc[mi][j] = p;
      sum += p;
    }
  sum += __shfl_xor(sum, 16, 64);
  sum += __shfl_xor(sum, 32, 64);
  float inv = 1.0f / sum;

#pragma unroll
  for (int mi = 0; mi < 16; ++mi) {
    uint2 v;
    v.x = pack2(sacc[mi][0] * inv, sacc[mi][1] * inv);
    v.y = pack2(sacc[mi][2] * inv, sacc[mi][3] * inv);
    int off = (q * 512 + mi * 32 + g * 8) ^ ((q & 7) << 4);
    *(uint2*)(smem + 81920 + off) = v;
  }
  __syncthreads();

  f32x4 oacc[4] = {};
#pragma unroll
  for (int ks = 0; ks < 8; ++ks) {
    int offa = (q * 512 + ks * 64 + g * 16) ^ ((q & 7) << 4);
    bf16x8 pa = *(const bf16x8*)(smem + 81920 + offa);
#pragma unroll
    for (int ni = 0; ni < 4; ++ni) {
      int d = ni * 16 + c16;
      int offb = (d * 512 + ks * 64 + g * 16) ^ ((d & 7) << 4);
      bf16x8 vb = *(const bf16x8*)(smem + 32768 + offb);
      oacc[ni] = __builtin_amdgcn_mfma_f32_16x16x32_bf16(pa, vb, oacc[ni],
                                                         0, 0, 0);
    }
  }

  bf16* Orow = O + ((size_t)b * 4096 + n0 + w * 16) * 512 + h * 64;
#pragma unroll
  for (int ni = 0; ni < 4; ++ni)
#pragma unroll
    for (int j = 0; j < 4; ++j)
      Orow[(size_t)(g * 4 + j) * 512 + ni * 16 + c16] = (bf16)oacc[ni][j];
}

// ---------------------------------------------------------------------------
extern "C" void kernel_launch(void* const* d_in, const int* in_sizes, int n_in,
                              void* d_out, int out_size, void* d_ws,
                              size_t ws_size, hipStream_t stream) {
  const float* X = (const float*)d_in[0];
  const float* S = (const float*)d_in[1];
  const float* Wq = (const float*)d_in[2];
  const float* Wk = (const float*)d_in[3];
  const float* Wv = (const float*)d_in[4];
  const float* Wo = (const float*)d_in[5];
  const float* temp = (const float*)d_in[6];
  float* out = (float*)d_out;

  char* ws = (char*)d_ws;
  bf16* Qws = (bf16*)ws;                      // 32768*512*2 = 33,554,432 B
  bf16* Kws = (bf16*)(ws + 33554432);         //  2048*512*2 =  2,097,152 B
  bf16* Vtws = (bf16*)(ws + 35651584);        //  8*8*64*256*2 = 2,097,152 B
  bf16* Wqb = (bf16*)(ws + 37748736);         //  512*512*2 = 524,288 B each
  bf16* Wkb = (bf16*)(ws + 38273024);
  bf16* Wvb = (bf16*)(ws + 38797312);
  bf16* Wob = (bf16*)(ws + 39321600);

  // Xb/Sb scratch inside d_out (67.1 MB f32): dead before out_gemm writes.
  bf16* Xb = (bf16*)d_out;                    // 33,554,432 B
  bf16* Sb = (bf16*)((char*)d_out + 33554432);  // 2,097,152 B

  cvt_all<<<dim3(9216), dim3(256), 0, stream>>>(X, S, Wq, Wk, Wv, Wo, Xb, Sb,
                                                Wqb, Wkb, Wvb, Wob);
  proj_all<<<dim3(1152), dim3(256), 0, stream>>>(Xb, Sb, Wqb, Wkb, Wvb, Qws,
                                                 Kws, Vtws);
  attn_fused<<<dim3(2048), dim3(512), 0, stream>>>(Qws, Kws, Vtws, temp, Qws);
  out_gemm<<<dim3(1024), dim3(256), 0, stream>>>(Qws, Wob, X, out);
}

// Round 13
// 155.045 us; speedup vs baseline: 1.0153x; 1.0153x over previous
//
#include <hip/hip_runtime.h>
#include <hip/hip_bf16.h>

// MDTA (multi-head cross attention with l2-normed q/k) for MI355X.
// B=8, N=4096, Ktok=256, C=512, H=8, D=64. Inputs f32, output f32.
//
// R8 187.9 -> R9 153.1 -> R10 167.8 -> R11 151.2 -> R12 157.4.
// R12 diagnosis: both GEMMs drain vmcnt(0) at every __syncthreads -> ~900cyc
// HBM latency exposed per BK=32 iter (16 MFMA can't cover it).
// R13: counted-vmcnt pipeline (T4): issue stage t+1, s_waitcnt vmcnt(4)
// (stage-t only), raw s_barrier, compute, raw s_barrier. Loads for t+1 stay
// in flight across barriers. Applied to proj_all and out_gemm.
//
// Pipeline: cvt_all (W,X,S->bf16) -> proj_all -> attn_fused -> out_gemm.

typedef __bf16 bf16;
typedef __attribute__((ext_vector_type(8))) __bf16 bf16x8;
typedef __attribute__((ext_vector_type(4))) float f32x4;

__device__ __forceinline__ void gload_lds16(const void* g, void* l) {
  __builtin_amdgcn_global_load_lds(
      (__attribute__((address_space(1))) void*)g,
      (__attribute__((address_space(3))) void*)l, 16, 0, 0);
}

__device__ __forceinline__ unsigned pack2(float a, float b) {
  unsigned short x = __builtin_bit_cast(unsigned short, (bf16)a);
  unsigned short y = __builtin_bit_cast(unsigned short, (bf16)b);
  return (unsigned)x | ((unsigned)y << 16);
}

// ---------------------------------------------------------------------------
// Convert X (2097152 chunks), S (131072), Wq/Wk/Wv/Wo (32768 each) to bf16.
// ---------------------------------------------------------------------------
__global__ __launch_bounds__(256) void cvt_all(
    const float* __restrict__ X, const float* __restrict__ S,
    const float* __restrict__ Wq, const float* __restrict__ Wk,
    const float* __restrict__ Wv, const float* __restrict__ Wo,
    bf16* __restrict__ Xb, bf16* __restrict__ Sb, bf16* __restrict__ Wqb,
    bf16* __restrict__ Wkb, bf16* __restrict__ Wvb, bf16* __restrict__ Wob) {
  int i = blockIdx.x * 256 + threadIdx.x;
  const float* src;
  bf16* dst;
  int r;
  if (i < 2097152) {
    src = X; dst = Xb; r = i;
  } else if (i < 2228224) {
    src = S; dst = Sb; r = i - 2097152;
  } else {
    int j = i - 2228224;
    int w = j >> 15;
    r = j & 32767;
    src = (w == 0) ? Wq : (w == 1) ? Wk : (w == 2) ? Wv : Wo;
    dst = (w == 0) ? Wqb : (w == 1) ? Wkb : (w == 2) ? Wvb : Wob;
  }
  float4 a = *(const float4*)(src + (size_t)r * 8);
  float4 b = *(const float4*)(src + (size_t)r * 8 + 4);
  uint4 v;
  v.x = pack2(a.x, a.y);
  v.y = pack2(a.z, a.w);
  v.z = pack2(b.x, b.y);
  v.w = pack2(b.z, b.w);
  *(uint4*)(dst + (size_t)r * 8) = v;
}

// ---------------------------------------------------------------------------
// Fused Q/K/V projection, all-bf16. 128x128 tile, BK=32, 16 iters,
// gload_lds double-buffer with COUNTED vmcnt (loads for t+1 in flight across
// raw barriers). 32 KB LDS -> ~5 blocks/CU. XCD swizzle.
// ---------------------------------------------------------------------------
__global__ __launch_bounds__(256) void proj_all(
    const bf16* __restrict__ Xb, const bf16* __restrict__ Sb,
    const bf16* __restrict__ Wqb, const bf16* __restrict__ Wkb,
    const bf16* __restrict__ Wvb, bf16* __restrict__ Q,
    bf16* __restrict__ Kn, bf16* __restrict__ Vt) {
  __shared__ __align__(16) bf16 As[2][128 * 32];
  __shared__ __align__(16) bf16 Bs[2][128 * 32];

  const int lg = (blockIdx.x & 7) * 144 + (blockIdx.x >> 3);

  const bf16* A;
  const bf16* W;
  int m0, kind;  // 0=Q, 1=K, 2=V
  if (lg < 1024) {
    kind = 0; A = Xb; W = Wqb; m0 = (lg >> 2) * 128;
  } else if (lg < 1088) {
    kind = 1; A = Sb; W = Wkb; m0 = ((lg - 1024) >> 2) * 128;
  } else {
    kind = 2; A = Sb; W = Wvb; m0 = ((lg - 1088) >> 2) * 128;
  }
  const int n0 = (lg & 3) * 128;

  const int tid = threadIdx.x;
  const int wid = tid >> 6, lane = tid & 63;
  const int wr = wid >> 1, wc = wid & 1;
  const int g = lane >> 4, c16 = lane & 15;
  const int c0 = tid, c1 = 256 + tid;
  const int r0 = c0 >> 2, cc0 = c0 & 3;
  const int r1 = c1 >> 2, cc1 = c1 & 3;

  f32x4 acc[4][4] = {};

  // prologue: stage 0 -> buf 0 (4 loads/thread)
  gload_lds16(A + (size_t)(m0 + r0) * 512 + cc0 * 8, As[0] + (tid & ~63) * 8);
  gload_lds16(A + (size_t)(m0 + r1) * 512 + cc1 * 8,
              As[0] + (256 + (tid & ~63)) * 8);
  gload_lds16(W + (size_t)(n0 + r0) * 512 + cc0 * 8, Bs[0] + (tid & ~63) * 8);
  gload_lds16(W + (size_t)(n0 + r1) * 512 + cc1 * 8,
              Bs[0] + (256 + (tid & ~63)) * 8);

  int cur = 0;
  for (int t = 0; t < 15; ++t) {
    const int kb = (t + 1) * 32;
    gload_lds16(A + (size_t)(m0 + r0) * 512 + kb + cc0 * 8,
                As[cur ^ 1] + (tid & ~63) * 8);
    gload_lds16(A + (size_t)(m0 + r1) * 512 + kb + cc1 * 8,
                As[cur ^ 1] + (256 + (tid & ~63)) * 8);
    gload_lds16(W + (size_t)(n0 + r0) * 512 + kb + cc0 * 8,
                Bs[cur ^ 1] + (tid & ~63) * 8);
    gload_lds16(W + (size_t)(n0 + r1) * 512 + kb + cc1 * 8,
                Bs[cur ^ 1] + (256 + (tid & ~63)) * 8);
    asm volatile("s_waitcnt vmcnt(4)" ::: "memory");  // stage t done
    __builtin_amdgcn_s_barrier();
    bf16x8 af[4], bfr[4];
#pragma unroll
    for (int mi = 0; mi < 4; ++mi)
      af[mi] =
          *(const bf16x8*)(As[cur] + (wr * 64 + mi * 16 + c16) * 32 + g * 8);
#pragma unroll
    for (int ni = 0; ni < 4; ++ni)
      bfr[ni] =
          *(const bf16x8*)(Bs[cur] + (wc * 64 + ni * 16 + c16) * 32 + g * 8);
#pragma unroll
    for (int mi = 0; mi < 4; ++mi)
#pragma unroll
      for (int ni = 0; ni < 4; ++ni)
        acc[mi][ni] = __builtin_amdgcn_mfma_f32_16x16x32_bf16(
            af[mi], bfr[ni], acc[mi][ni], 0, 0, 0);
    __builtin_amdgcn_s_barrier();  // all reads of buf cur done
    cur ^= 1;
  }
  // final iteration
  asm volatile("s_waitcnt vmcnt(0)" ::: "memory");
  __builtin_amdgcn_s_barrier();
  {
    bf16x8 af[4], bfr[4];
#pragma unroll
    for (int mi = 0; mi < 4; ++mi)
      af[mi] =
          *(const bf16x8*)(As[cur] + (wr * 64 + mi * 16 + c16) * 32 + g * 8);
#pragma unroll
    for (int ni = 0; ni < 4; ++ni)
      bfr[ni] =
          *(const bf16x8*)(Bs[cur] + (wc * 64 + ni * 16 + c16) * 32 + g * 8);
#pragma unroll
    for (int mi = 0; mi < 4; ++mi)
#pragma unroll
      for (int ni = 0; ni < 4; ++ni)
        acc[mi][ni] = __builtin_amdgcn_mfma_f32_16x16x32_bf16(
            af[mi], bfr[ni], acc[mi][ni], 0, 0, 0);
  }

  // ---- epilogue. C/D frag: col = lane&15, row = (lane>>4)*4 + j   [m89]
  if (kind != 2) {
    bf16* C = (kind == 0) ? Q : Kn;
#pragma unroll
    for (int mi = 0; mi < 4; ++mi) {
      float ss[4];
#pragma unroll
      for (int j = 0; j < 4; ++j) {
        float s = 0.f;
#pragma unroll
        for (int ni = 0; ni < 4; ++ni) {
          float v = acc[mi][ni][j];
          s += v * v;
        }
        ss[j] = s;
      }
#pragma unroll
      for (int msk = 1; msk < 16; msk <<= 1)
#pragma unroll
        for (int j = 0; j < 4; ++j) ss[j] += __shfl_xor(ss[j], msk, 64);
      float inv[4];
#pragma unroll
      for (int j = 0; j < 4; ++j) inv[j] = rsqrtf(fmaxf(ss[j], 1e-24f));
#pragma unroll
      for (int ni = 0; ni < 4; ++ni)
#pragma unroll
        for (int j = 0; j < 4; ++j) {
          size_t idx = (size_t)(m0 + wr * 64 + mi * 16 + g * 4 + j) * 512 +
                       n0 + wc * 64 + ni * 16 + c16;
          C[idx] = (bf16)(acc[mi][ni][j] * inv[j]);
        }
    }
  } else {
#pragma unroll
    for (int mi = 0; mi < 4; ++mi) {
      int m = m0 + wr * 64 + mi * 16 + g * 4;  // +j
      int b = m >> 8, tt = m & 255;
#pragma unroll
      for (int ni = 0; ni < 4; ++ni) {
        int col = n0 + wc * 64 + ni * 16 + c16;
        int h = col >> 6, d = col & 63;
        uint2 v;
        v.x = pack2(acc[mi][ni][0], acc[mi][ni][1]);
        v.y = pack2(acc[mi][ni][2], acc[mi][ni][3]);
        *(uint2*)(Vt + ((size_t)((b * 8 + h) * 64 + d) * 256 + tt)) = v;
      }
    }
  }
}

// ---------------------------------------------------------------------------
// out = X + O @ Wo^T, f32 output. Same counted-vmcnt pipeline.
// ---------------------------------------------------------------------------
__global__ __launch_bounds__(256) void out_gemm(
    const bf16* __restrict__ O, const bf16* __restrict__ Wob,
    const float* __restrict__ Xres, float* __restrict__ out) {
  __shared__ __align__(16) bf16 As[2][128 * 32];
  __shared__ __align__(16) bf16 Bs[2][128 * 32];

  const int lg = (blockIdx.x & 7) * 128 + (blockIdx.x >> 3);  // XCD swizzle
  const int m0 = (lg >> 2) * 128, n0 = (lg & 3) * 128;

  const int tid = threadIdx.x;
  const int wid = tid >> 6, lane = tid & 63;
  const int wr = wid >> 1, wc = wid & 1;
  const int g = lane >> 4, c16 = lane & 15;
  const int c0 = tid, c1 = 256 + tid;
  const int r0 = c0 >> 2, cc0 = c0 & 3;
  const int r1 = c1 >> 2, cc1 = c1 & 3;

  f32x4 acc[4][4] = {};

  gload_lds16(O + (size_t)(m0 + r0) * 512 + cc0 * 8, As[0] + (tid & ~63) * 8);
  gload_lds16(O + (size_t)(m0 + r1) * 512 + cc1 * 8,
              As[0] + (256 + (tid & ~63)) * 8);
  gload_lds16(Wob + (size_t)(n0 + r0) * 512 + cc0 * 8,
              Bs[0] + (tid & ~63) * 8);
  gload_lds16(Wob + (size_t)(n0 + r1) * 512 + cc1 * 8,
              Bs[0] + (256 + (tid & ~63)) * 8);

  int cur = 0;
  for (int t = 0; t < 15; ++t) {
    const int kb = (t + 1) * 32;
    gload_lds16(O + (size_t)(m0 + r0) * 512 + kb + cc0 * 8,
                As[cur ^ 1] + (tid & ~63) * 8);
    gload_lds16(O + (size_t)(m0 + r1) * 512 + kb + cc1 * 8,
                As[cur ^ 1] + (256 + (tid & ~63)) * 8);
    gload_lds16(Wob + (size_t)(n0 + r0) * 512 + kb + cc0 * 8,
                Bs[cur ^ 1] + (tid & ~63) * 8);
    gload_lds16(Wob + (size_t)(n0 + r1) * 512 + kb + cc1 * 8,
                Bs[cur ^ 1] + (256 + (tid & ~63)) * 8);
    asm volatile("s_waitcnt vmcnt(4)" ::: "memory");
    __builtin_amdgcn_s_barrier();
    bf16x8 af[4], bfr[4];
#pragma unroll
    for (int mi = 0; mi < 4; ++mi)
      af[mi] =
          *(const bf16x8*)(As[cur] + (wr * 64 + mi * 16 + c16) * 32 + g * 8);
#pragma unroll
    for (int ni = 0; ni < 4; ++ni)
      bfr[ni] =
          *(const bf16x8*)(Bs[cur] + (wc * 64 + ni * 16 + c16) * 32 + g * 8);
#pragma unroll
    for (int mi = 0; mi < 4; ++mi)
#pragma unroll
      for (int ni = 0; ni < 4; ++ni)
        acc[mi][ni] = __builtin_amdgcn_mfma_f32_16x16x32_bf16(
            af[mi], bfr[ni], acc[mi][ni], 0, 0, 0);
    __builtin_amdgcn_s_barrier();
    cur ^= 1;
  }
  asm volatile("s_waitcnt vmcnt(0)" ::: "memory");
  __builtin_amdgcn_s_barrier();
  {
    bf16x8 af[4], bfr[4];
#pragma unroll
    for (int mi = 0; mi < 4; ++mi)
      af[mi] =
          *(const bf16x8*)(As[cur] + (wr * 64 + mi * 16 + c16) * 32 + g * 8);
#pragma unroll
    for (int ni = 0; ni < 4; ++ni)
      bfr[ni] =
          *(const bf16x8*)(Bs[cur] + (wc * 64 + ni * 16 + c16) * 32 + g * 8);
#pragma unroll
    for (int mi = 0; mi < 4; ++mi)
#pragma unroll
      for (int ni = 0; ni < 4; ++ni)
        acc[mi][ni] = __builtin_amdgcn_mfma_f32_16x16x32_bf16(
            af[mi], bfr[ni], acc[mi][ni], 0, 0, 0);
  }

#pragma unroll
  for (int mi = 0; mi < 4; ++mi)
#pragma unroll
    for (int ni = 0; ni < 4; ++ni)
#pragma unroll
      for (int j = 0; j < 4; ++j) {
        size_t idx = (size_t)(m0 + wr * 64 + mi * 16 + g * 4 + j) * 512 + n0 +
                     wc * 64 + ni * 16 + c16;
        out[idx] = acc[mi][ni][j] + Xres[idx];
      }
}

// ---------------------------------------------------------------------------
// Fused attention (unchanged, proven). Block = (b,h,128 q), 512 thr.
// ---------------------------------------------------------------------------
__global__ __launch_bounds__(512) void attn_fused(
    const bf16* __restrict__ Qn, const bf16* __restrict__ Kn,
    const bf16* __restrict__ Vt, const float* __restrict__ temp,
    bf16* __restrict__ O) {
  __shared__ __align__(16) char smem[147456];
  // [0,32768) Ksm [256t][64d] | [32768,65536) Vsm [64d][256t]
  // [65536,81920) Qsm [128q][64d] | [81920,147456) Psm [128q][256k]

  const int tid = threadIdx.x;
  const int w = tid >> 6, lane = tid & 63;
  const int g = lane >> 4, c16 = lane & 15;
  const int bx = blockIdx.x;
  const int nt = bx & 31, h = (bx >> 5) & 7, b = bx >> 8;
  const int n0 = nt * 128;

  {
    const bf16* Ksrc = Kn + ((size_t)b * 256) * 512 + h * 64;
#pragma unroll
    for (int it = 0; it < 4; ++it) {
      int c = it * 512 + tid;
      int t = c >> 3, dc = c & 7;
      int4 v = *(const int4*)(Ksrc + (size_t)t * 512 + dc * 8);
      int off = (t * 128 + dc * 16) ^ ((t & 7) << 4);
      *(int4*)(smem + off) = v;
    }
    const bf16* Vsrc = Vt + (size_t)((b * 8 + h) * 64) * 256;
#pragma unroll
    for (int it = 0; it < 4; ++it) {
      int c = it * 512 + tid;
      int d = c >> 5, tc = c & 31;
      int4 v = *(const int4*)(Vsrc + (size_t)d * 256 + tc * 8);
      int off = (d * 512 + tc * 16) ^ ((d & 7) << 4);
      *(int4*)(smem + 32768 + off) = v;
    }
    const bf16* Qsrc = Qn + ((size_t)b * 4096 + n0) * 512 + h * 64;
#pragma unroll
    for (int it = 0; it < 2; ++it) {
      int c = it * 512 + tid;
      int q = c >> 3, dc = c & 7;
      int4 v = *(const int4*)(Qsrc + (size_t)q * 512 + dc * 8);
      int off = (q * 128 + dc * 16) ^ ((q & 7) << 4);
      *(int4*)(smem + 65536 + off) = v;
    }
  }
  __syncthreads();

  const int q = w * 16 + c16;

  f32x4 sacc[16] = {};
  bf16x8 qf[2];
#pragma unroll
  for (int s = 0; s < 2; ++s) {
    int off = (q * 128 + s * 64 + g * 16) ^ ((q & 7) << 4);
    qf[s] = *(const bf16x8*)(smem + 65536 + off);
  }
#pragma unroll
  for (int mi = 0; mi < 16; ++mi) {
#pragma unroll
    for (int s = 0; s < 2; ++s) {
      int t = mi * 16 + c16;
      int off = (t * 128 + s * 64 + g * 16) ^ ((t & 7) << 4);
      bf16x8 kf = *(const bf16x8*)(smem + off);
      sacc[mi] = __builtin_amdgcn_mfma_f32_16x16x32_bf16(kf, qf[s], sacc[mi],
                                                         0, 0, 0);
    }
  }

  float tv = temp[h];
  float mx = -1e30f;
#pragma unroll
  for (int mi = 0; mi < 16; ++mi)
#pragma unroll
    for (int j = 0; j < 4; ++j) {
      sacc[mi][j] *= tv;
      mx = fmaxf(mx, sacc[mi][j]);
    }
  mx = fmaxf(mx, __shfl_xor(mx, 16, 64));
  mx = fmaxf(mx, __shfl_xor(mx, 32, 64));
  float sum = 0.f;
#pragma unroll
  for (int mi = 0; mi < 16; ++mi)
#pragma unroll
    for (int j = 0; j < 4; ++j) {
      float p = __expf(sacc[mi][j] - mx);
      sacc[mi][j] = p;
      sum += p;
    }
  sum += __shfl_xor(sum, 16, 64);
  sum += __shfl_xor(sum, 32, 64);
  float inv = 1.0f / sum;

#pragma unroll
  for (int mi = 0; mi < 16; ++mi) {
    uint2 v;
    v.x = pack2(sacc[mi][0] * inv, sacc[mi][1] * inv);
    v.y = pack2(sacc[mi][2] * inv, sacc[mi][3] * inv);
    int off = (q * 512 + mi * 32 + g * 8) ^ ((q & 7) << 4);
    *(uint2*)(smem + 81920 + off) = v;
  }
  __syncthreads();

  f32x4 oacc[4] = {};
#pragma unroll
  for (int ks = 0; ks < 8; ++ks) {
    int offa = (q * 512 + ks * 64 + g * 16) ^ ((q & 7) << 4);
    bf16x8 pa = *(const bf16x8*)(smem + 81920 + offa);
#pragma unroll
    for (int ni = 0; ni < 4; ++ni) {
      int d = ni * 16 + c16;
      int offb = (d * 512 + ks * 64 + g * 16) ^ ((d & 7) << 4);
      bf16x8 vb = *(const bf16x8*)(smem + 32768 + offb);
      oacc[ni] = __builtin_amdgcn_mfma_f32_16x16x32_bf16(pa, vb, oacc[ni],
                                                         0, 0, 0);
    }
  }

  bf16* Orow = O + ((size_t)b * 4096 + n0 + w * 16) * 512 + h * 64;
#pragma unroll
  for (int ni = 0; ni < 4; ++ni)
#pragma unroll
    for (int j = 0; j < 4; ++j)
      Orow[(size_t)(g * 4 + j) * 512 + ni * 16 + c16] = (bf16)oacc[ni][j];
}

// ---------------------------------------------------------------------------
extern "C" void kernel_launch(void* const* d_in, const int* in_sizes, int n_in,
                              void* d_out, int out_size, void* d_ws,
                              size_t ws_size, hipStream_t stream) {
  const float* X = (const float*)d_in[0];
  const float* S = (const float*)d_in[1];
  const float* Wq = (const float*)d_in[2];
  const float* Wk = (const float*)d_in[3];
  const float* Wv = (const float*)d_in[4];
  const float* Wo = (const float*)d_in[5];
  const float* temp = (const float*)d_in[6];
  float* out = (float*)d_out;

  char* ws = (char*)d_ws;
  bf16* Qws = (bf16*)ws;                      // 32768*512*2 = 33,554,432 B
  bf16* Kws = (bf16*)(ws + 33554432);         //  2048*512*2 =  2,097,152 B
  bf16* Vtws = (bf16*)(ws + 35651584);        //  8*8*64*256*2 = 2,097,152 B
  bf16* Wqb = (bf16*)(ws + 37748736);         //  512*512*2 = 524,288 B each
  bf16* Wkb = (bf16*)(ws + 38273024);
  bf16* Wvb = (bf16*)(ws + 38797312);
  bf16* Wob = (bf16*)(ws + 39321600);

  // Xb/Sb scratch inside d_out (67.1 MB f32): dead before out_gemm writes.
  bf16* Xb = (bf16*)d_out;                      // 33,554,432 B
  bf16* Sb = (bf16*)((char*)d_out + 33554432);  //  2,097,152 B

  cvt_all<<<dim3(9216), dim3(256), 0, stream>>>(X, S, Wq, Wk, Wv, Wo, Xb, Sb,
                                                Wqb, Wkb, Wvb, Wob);
  proj_all<<<dim3(1152), dim3(256), 0, stream>>>(Xb, Sb, Wqb, Wkb, Wvb, Qws,
                                                 Kws, Vtws);
  attn_fused<<<dim3(2048), dim3(512), 0, stream>>>(Qws, Kws, Vtws, temp, Qws);
  out_gemm<<<dim3(1024), dim3(256), 0, stream>>>(Qws, Wob, X, out);
}

// Round 14
// 134.870 us; speedup vs baseline: 1.1672x; 1.1496x over previous
//
#include <hip/hip_runtime.h>
#include <hip/hip_bf16.h>

// MDTA (multi-head cross attention with l2-normed q/k) for MI355X.
// B=8, N=4096, Ktok=256, C=512, H=8, D=64. Inputs f32, output f32.
//
// R8 187.9 -> R9 153.1 -> R10 167.8 -> R11 151.2 -> R12 157.4 -> R13 155.0.
// R13 null: depth-1 counted vmcnt changed nothing. R14:
//  (a) depth-3 pipeline (3 LDS bufs, vmcnt(8) steady state) in both GEMMs;
//  (b) coalesced epilogues via per-wave swizzled LDS re-tile:
//      out_gemm f32x4 loads/stores, proj bf16x8 stores, attn O bf16x8.
//
// Pipeline: cvt_all (W,X,S->bf16) -> proj_all -> attn_fused -> out_gemm.

typedef __bf16 bf16;
typedef __attribute__((ext_vector_type(8))) __bf16 bf16x8;
typedef __attribute__((ext_vector_type(4))) float f32x4;

__device__ __forceinline__ void gload_lds16(const void* g, void* l) {
  __builtin_amdgcn_global_load_lds(
      (__attribute__((address_space(1))) void*)g,
      (__attribute__((address_space(3))) void*)l, 16, 0, 0);
}

__device__ __forceinline__ unsigned pack2(float a, float b) {
  unsigned short x = __builtin_bit_cast(unsigned short, (bf16)a);
  unsigned short y = __builtin_bit_cast(unsigned short, (bf16)b);
  return (unsigned)x | ((unsigned)y << 16);
}

// ---------------------------------------------------------------------------
// Convert X (2097152 chunks), S (131072), Wq/Wk/Wv/Wo (32768 each) to bf16.
// ---------------------------------------------------------------------------
__global__ __launch_bounds__(256) void cvt_all(
    const float* __restrict__ X, const float* __restrict__ S,
    const float* __restrict__ Wq, const float* __restrict__ Wk,
    const float* __restrict__ Wv, const float* __restrict__ Wo,
    bf16* __restrict__ Xb, bf16* __restrict__ Sb, bf16* __restrict__ Wqb,
    bf16* __restrict__ Wkb, bf16* __restrict__ Wvb, bf16* __restrict__ Wob) {
  int i = blockIdx.x * 256 + threadIdx.x;
  const float* src;
  bf16* dst;
  int r;
  if (i < 2097152) {
    src = X; dst = Xb; r = i;
  } else if (i < 2228224) {
    src = S; dst = Sb; r = i - 2097152;
  } else {
    int j = i - 2228224;
    int w = j >> 15;
    r = j & 32767;
    src = (w == 0) ? Wq : (w == 1) ? Wk : (w == 2) ? Wv : Wo;
    dst = (w == 0) ? Wqb : (w == 1) ? Wkb : (w == 2) ? Wvb : Wob;
  }
  float4 a = *(const float4*)(src + (size_t)r * 8);
  float4 b = *(const float4*)(src + (size_t)r * 8 + 4);
  uint4 v;
  v.x = pack2(a.x, a.y);
  v.y = pack2(a.z, a.w);
  v.z = pack2(b.x, b.y);
  v.w = pack2(b.z, b.w);
  *(uint4*)(dst + (size_t)r * 8) = v;
}

// ---------------------------------------------------------------------------
// Fused Q/K/V projection, all-bf16. 128x128 tile, BK=32, 16 stages,
// depth-3 gload_lds pipeline (vmcnt(8) steady state, loads span barriers).
// Epilogue: l2norm -> per-wave swizzled LDS re-tile -> bf16x8 stores.
// ---------------------------------------------------------------------------
__global__ __launch_bounds__(256) void proj_all(
    const bf16* __restrict__ Xb, const bf16* __restrict__ Sb,
    const bf16* __restrict__ Wqb, const bf16* __restrict__ Wkb,
    const bf16* __restrict__ Wvb, bf16* __restrict__ Q,
    bf16* __restrict__ Kn, bf16* __restrict__ Vt) {
  __shared__ __align__(16) char smem[49152];  // 3x(As 8KB + Bs 8KB)

  const int lg = (blockIdx.x & 7) * 144 + (blockIdx.x >> 3);

  const bf16* A;
  const bf16* W;
  int m0, kind;  // 0=Q, 1=K, 2=V
  if (lg < 1024) {
    kind = 0; A = Xb; W = Wqb; m0 = (lg >> 2) * 128;
  } else if (lg < 1088) {
    kind = 1; A = Sb; W = Wkb; m0 = ((lg - 1024) >> 2) * 128;
  } else {
    kind = 2; A = Sb; W = Wvb; m0 = ((lg - 1088) >> 2) * 128;
  }
  const int n0 = (lg & 3) * 128;

  const int tid = threadIdx.x;
  const int wid = tid >> 6, lane = tid & 63;
  const int wr = wid >> 1, wc = wid & 1;
  const int g = lane >> 4, c16 = lane & 15;
  const int r0 = tid >> 2, cc0 = tid & 3;
  const int r1 = (256 + tid) >> 2, cc1 = tid & 3;
  const int dst0 = (tid & ~63) * 16, dst1 = (256 + (tid & ~63)) * 16;

  f32x4 acc[4][4] = {};

#define PSTAGE(kb, buf)                                                     \
  {                                                                         \
    char* as = smem + (buf) * 8192;                                         \
    char* bs = smem + 24576 + (buf) * 8192;                                 \
    gload_lds16(A + (size_t)(m0 + r0) * 512 + (kb) + cc0 * 8, as + dst0);   \
    gload_lds16(A + (size_t)(m0 + r1) * 512 + (kb) + cc1 * 8, as + dst1);   \
    gload_lds16(W + (size_t)(n0 + r0) * 512 + (kb) + cc0 * 8, bs + dst0);   \
    gload_lds16(W + (size_t)(n0 + r1) * 512 + (kb) + cc1 * 8, bs + dst1);   \
  }

#define PCOMPUTE(buf)                                                       \
  {                                                                         \
    const bf16* as = (const bf16*)(smem + (buf) * 8192);                    \
    const bf16* bs = (const bf16*)(smem + 24576 + (buf) * 8192);            \
    bf16x8 af[4], bfr[4];                                                   \
    _Pragma("unroll") for (int mi = 0; mi < 4; ++mi) af[mi] =               \
        *(const bf16x8*)(as + (wr * 64 + mi * 16 + c16) * 32 + g * 8);      \
    _Pragma("unroll") for (int ni = 0; ni < 4; ++ni) bfr[ni] =              \
        *(const bf16x8*)(bs + (wc * 64 + ni * 16 + c16) * 32 + g * 8);      \
    _Pragma("unroll") for (int mi = 0; mi < 4; ++mi)                        \
        _Pragma("unroll") for (int ni = 0; ni < 4; ++ni) acc[mi][ni] =      \
            __builtin_amdgcn_mfma_f32_16x16x32_bf16(af[mi], bfr[ni],        \
                                                    acc[mi][ni], 0, 0, 0);  \
  }

  PSTAGE(0, 0);
  PSTAGE(32, 1);
  int bufc = 0;
  for (int t = 0; t < 14; ++t) {
    int bufn = bufc + 2;
    if (bufn >= 3) bufn -= 3;
    PSTAGE((t + 2) * 32, bufn);
    asm volatile("s_waitcnt vmcnt(8)" ::: "memory");
    __builtin_amdgcn_s_barrier();
    PCOMPUTE(bufc);
    __builtin_amdgcn_s_barrier();
    if (++bufc == 3) bufc = 0;
  }
  asm volatile("s_waitcnt vmcnt(4)" ::: "memory");
  __builtin_amdgcn_s_barrier();
  PCOMPUTE(bufc);
  __builtin_amdgcn_s_barrier();
  if (++bufc == 3) bufc = 0;
  asm volatile("s_waitcnt vmcnt(0)" ::: "memory");
  __builtin_amdgcn_s_barrier();
  PCOMPUTE(bufc);

  __syncthreads();  // release K-loop LDS for epilogue re-tile

  // ---- epilogue. C/D frag: col = lane&15, row = (lane>>4)*4 + j   [m89]
  if (kind != 2) {
    bf16* C = (kind == 0) ? Q : Kn;
    char* eps = smem + wid * 8192;  // wave-private 64x64 bf16 tile
#pragma unroll
    for (int mi = 0; mi < 4; ++mi) {
      float ss[4];
#pragma unroll
      for (int j = 0; j < 4; ++j) {
        float s = 0.f;
#pragma unroll
        for (int ni = 0; ni < 4; ++ni) {
          float v = acc[mi][ni][j];
          s += v * v;
        }
        ss[j] = s;
      }
#pragma unroll
      for (int msk = 1; msk < 16; msk <<= 1)
#pragma unroll
        for (int j = 0; j < 4; ++j) ss[j] += __shfl_xor(ss[j], msk, 64);
      float inv[4];
#pragma unroll
      for (int j = 0; j < 4; ++j) inv[j] = rsqrtf(fmaxf(ss[j], 1e-24f));
#pragma unroll
      for (int ni = 0; ni < 4; ++ni)
#pragma unroll
        for (int j = 0; j < 4; ++j) {
          int row = mi * 16 + g * 4 + j, col = ni * 16 + c16;
          int off = (row * 128 + col * 2) ^ ((row & 7) << 4);
          *(bf16*)(eps + off) = (bf16)(acc[mi][ni][j] * inv[j]);
        }
    }
    asm volatile("s_waitcnt lgkmcnt(0)" ::: "memory");
#pragma unroll
    for (int it = 0; it < 8; ++it) {
      int c = it * 64 + lane;
      int row = c >> 3, ch = c & 7;
      int off = (row * 128 + ch * 16) ^ ((row & 7) << 4);
      bf16x8 v = *(const bf16x8*)(eps + off);
      *(bf16x8*)(C + (size_t)(m0 + wr * 64 + row) * 512 + n0 + wc * 64 +
                 ch * 8) = v;
    }
  } else {
    // transposed store into Vt[b][h][d][t] (M=2048): 8B stores, small.
#pragma unroll
    for (int mi = 0; mi < 4; ++mi) {
      int m = m0 + wr * 64 + mi * 16 + g * 4;  // +j
      int b = m >> 8, tt = m & 255;
#pragma unroll
      for (int ni = 0; ni < 4; ++ni) {
        int col = n0 + wc * 64 + ni * 16 + c16;
        int h = col >> 6, d = col & 63;
        uint2 v;
        v.x = pack2(acc[mi][ni][0], acc[mi][ni][1]);
        v.y = pack2(acc[mi][ni][2], acc[mi][ni][3]);
        *(uint2*)(Vt + ((size_t)((b * 8 + h) * 64 + d) * 256 + tt)) = v;
      }
    }
  }
#undef PSTAGE
#undef PCOMPUTE
}

// ---------------------------------------------------------------------------
// out = X + O @ Wo^T, f32 output. Depth-3 pipeline + f32x4 re-tiled epilogue.
// ---------------------------------------------------------------------------
__global__ __launch_bounds__(256) void out_gemm(
    const bf16* __restrict__ O, const bf16* __restrict__ Wob,
    const float* __restrict__ Xres, float* __restrict__ out) {
  __shared__ __align__(16) char smem[49152];

  const int lg = (blockIdx.x & 7) * 128 + (blockIdx.x >> 3);  // XCD swizzle
  const int m0 = (lg >> 2) * 128, n0 = (lg & 3) * 128;

  const int tid = threadIdx.x;
  const int wid = tid >> 6, lane = tid & 63;
  const int wr = wid >> 1, wc = wid & 1;
  const int g = lane >> 4, c16 = lane & 15;
  const int r0 = tid >> 2, cc0 = tid & 3;
  const int r1 = (256 + tid) >> 2, cc1 = tid & 3;
  const int dst0 = (tid & ~63) * 16, dst1 = (256 + (tid & ~63)) * 16;

  f32x4 acc[4][4] = {};

#define OSTAGE(kb, buf)                                                      \
  {                                                                          \
    char* as = smem + (buf) * 8192;                                          \
    char* bs = smem + 24576 + (buf) * 8192;                                  \
    gload_lds16(O + (size_t)(m0 + r0) * 512 + (kb) + cc0 * 8, as + dst0);    \
    gload_lds16(O + (size_t)(m0 + r1) * 512 + (kb) + cc1 * 8, as + dst1);    \
    gload_lds16(Wob + (size_t)(n0 + r0) * 512 + (kb) + cc0 * 8, bs + dst0);  \
    gload_lds16(Wob + (size_t)(n0 + r1) * 512 + (kb) + cc1 * 8, bs + dst1);  \
  }

#define OCOMPUTE(buf)                                                       \
  {                                                                         \
    const bf16* as = (const bf16*)(smem + (buf) * 8192);                    \
    const bf16* bs = (const bf16*)(smem + 24576 + (buf) * 8192);            \
    bf16x8 af[4], bfr[4];                                                   \
    _Pragma("unroll") for (int mi = 0; mi < 4; ++mi) af[mi] =               \
        *(const bf16x8*)(as + (wr * 64 + mi * 16 + c16) * 32 + g * 8);      \
    _Pragma("unroll") for (int ni = 0; ni < 4; ++ni) bfr[ni] =              \
        *(const bf16x8*)(bs + (wc * 64 + ni * 16 + c16) * 32 + g * 8);      \
    _Pragma("unroll") for (int mi = 0; mi < 4; ++mi)                        \
        _Pragma("unroll") for (int ni = 0; ni < 4; ++ni) acc[mi][ni] =      \
            __builtin_amdgcn_mfma_f32_16x16x32_bf16(af[mi], bfr[ni],        \
                                                    acc[mi][ni], 0, 0, 0);  \
  }

  OSTAGE(0, 0);
  OSTAGE(32, 1);
  int bufc = 0;
  for (int t = 0; t < 14; ++t) {
    int bufn = bufc + 2;
    if (bufn >= 3) bufn -= 3;
    OSTAGE((t + 2) * 32, bufn);
    asm volatile("s_waitcnt vmcnt(8)" ::: "memory");
    __builtin_amdgcn_s_barrier();
    OCOMPUTE(bufc);
    __builtin_amdgcn_s_barrier();
    if (++bufc == 3) bufc = 0;
  }
  asm volatile("s_waitcnt vmcnt(4)" ::: "memory");
  __builtin_amdgcn_s_barrier();
  OCOMPUTE(bufc);
  __builtin_amdgcn_s_barrier();
  if (++bufc == 3) bufc = 0;
  asm volatile("s_waitcnt vmcnt(0)" ::: "memory");
  __builtin_amdgcn_s_barrier();
  OCOMPUTE(bufc);

  __syncthreads();  // release K-loop LDS for f32 re-tile

  // Epilogue: 2 passes x (32 rows x 64 cols f32) per wave, swizzled LDS,
  // then float4 X-load + add + float4 store (full-line writes).
  char* eps = smem + wid * 8192;
#pragma unroll
  for (int p = 0; p < 2; ++p) {
#pragma unroll
    for (int mm = 0; mm < 2; ++mm)
#pragma unroll
      for (int ni = 0; ni < 4; ++ni)
#pragma unroll
        for (int j = 0; j < 4; ++j) {
          int row = mm * 16 + g * 4 + j, col = ni * 16 + c16;
          int off = (row * 256 + col * 4) ^ ((row & 7) << 4);
          *(float*)(eps + off) = acc[p * 2 + mm][ni][j];
        }
    asm volatile("s_waitcnt lgkmcnt(0)" ::: "memory");
#pragma unroll
    for (int it = 0; it < 8; ++it) {
      int c = it * 64 + lane;
      int row = c >> 4, ch = c & 15;
      int off = (row * 256 + ch * 16) ^ ((row & 7) << 4);
      float4 v = *(const float4*)(eps + off);
      size_t gr = (size_t)(m0 + wr * 64 + p * 32 + row) * 512 + n0 +
                  wc * 64 + ch * 4;
      float4 x = *(const float4*)(Xres + gr);
      v.x += x.x;
      v.y += x.y;
      v.z += x.z;
      v.w += x.w;
      *(float4*)(out + gr) = v;
    }
    asm volatile("s_waitcnt lgkmcnt(0)" ::: "memory");
  }
#undef OSTAGE
#undef OCOMPUTE
}

// ---------------------------------------------------------------------------
// Fused attention. Block = (b,h,128 q), 512 thr. O-store now re-tiled via
// per-wave LDS slice (reuses Qsm region) -> bf16x8 coalesced stores.
// ---------------------------------------------------------------------------
__global__ __launch_bounds__(512) void attn_fused(
    const bf16* __restrict__ Qn, const bf16* __restrict__ Kn,
    const bf16* __restrict__ Vt, const float* __restrict__ temp,
    bf16* __restrict__ O) {
  __shared__ __align__(16) char smem[147456];
  // [0,32768) Ksm [256t][64d] | [32768,65536) Vsm [64d][256t]
  // [65536,81920) Qsm [128q][64d] (reused for O re-tile) |
  // [81920,147456) Psm [128q][256k]

  const int tid = threadIdx.x;
  const int w = tid >> 6, lane = tid & 63;
  const int g = lane >> 4, c16 = lane & 15;
  const int bx = blockIdx.x;
  const int nt = bx & 31, h = (bx >> 5) & 7, b = bx >> 8;
  const int n0 = nt * 128;

  {
    const bf16* Ksrc = Kn + ((size_t)b * 256) * 512 + h * 64;
#pragma unroll
    for (int it = 0; it < 4; ++it) {
      int c = it * 512 + tid;
      int t = c >> 3, dc = c & 7;
      int4 v = *(const int4*)(Ksrc + (size_t)t * 512 + dc * 8);
      int off = (t * 128 + dc * 16) ^ ((t & 7) << 4);
      *(int4*)(smem + off) = v;
    }
    const bf16* Vsrc = Vt + (size_t)((b * 8 + h) * 64) * 256;
#pragma unroll
    for (int it = 0; it < 4; ++it) {
      int c = it * 512 + tid;
      int d = c >> 5, tc = c & 31;
      int4 v = *(const int4*)(Vsrc + (size_t)d * 256 + tc * 8);
      int off = (d * 512 + tc * 16) ^ ((d & 7) << 4);
      *(int4*)(smem + 32768 + off) = v;
    }
    const bf16* Qsrc = Qn + ((size_t)b * 4096 + n0) * 512 + h * 64;
#pragma unroll
    for (int it = 0; it < 2; ++it) {
      int c = it * 512 + tid;
      int q = c >> 3, dc = c & 7;
      int4 v = *(const int4*)(Qsrc + (size_t)q * 512 + dc * 8);
      int off = (q * 128 + dc * 16) ^ ((q & 7) << 4);
      *(int4*)(smem + 65536 + off) = v;
    }
  }
  __syncthreads();

  const int q = w * 16 + c16;

  f32x4 sacc[16] = {};
  bf16x8 qf[2];
#pragma unroll
  for (int s = 0; s < 2; ++s) {
    int off = (q * 128 + s * 64 + g * 16) ^ ((q & 7) << 4);
    qf[s] = *(const bf16x8*)(smem + 65536 + off);
  }
#pragma unroll
  for (int mi = 0; mi < 16; ++mi) {
#pragma unroll
    for (int s = 0; s < 2; ++s) {
      int t = mi * 16 + c16;
      int off = (t * 128 + s * 64 + g * 16) ^ ((t & 7) << 4);
      bf16x8 kf = *(const bf16x8*)(smem + off);
      sacc[mi] = __builtin_amdgcn_mfma_f32_16x16x32_bf16(kf, qf[s], sacc[mi],
                                                         0, 0, 0);
    }
  }

  float tv = temp[h];
  float mx = -1e30f;
#pragma unroll
  for (int mi = 0; mi < 16; ++mi)
#pragma unroll
    for (int j = 0; j < 4; ++j) {
      sacc[mi][j] *= tv;
      mx = fmaxf(mx, sacc[mi][j]);
    }
  mx = fmaxf(mx, __shfl_xor(mx, 16, 64));
  mx = fmaxf(mx, __shfl_xor(mx, 32, 64));
  float sum = 0.f;
#pragma unroll
  for (int mi = 0; mi < 16; ++mi)
#pragma unroll
    for (int j = 0; j < 4; ++j) {
      float p = __expf(sacc[mi][j] - mx);
      sacc[mi][j] = p;
      sum += p;
    }
  sum += __shfl_xor(sum, 16, 64);
  sum += __shfl_xor(sum, 32, 64);
  float inv = 1.0f / sum;

#pragma unroll
  for (int mi = 0; mi < 16; ++mi) {
    uint2 v;
    v.x = pack2(sacc[mi][0] * inv, sacc[mi][1] * inv);
    v.y = pack2(sacc[mi][2] * inv, sacc[mi][3] * inv);
    int off = (q * 512 + mi * 32 + g * 8) ^ ((q & 7) << 4);
    *(uint2*)(smem + 81920 + off) = v;
  }
  __syncthreads();

  f32x4 oacc[4] = {};
#pragma unroll
  for (int ks = 0; ks < 8; ++ks) {
    int offa = (q * 512 + ks * 64 + g * 16) ^ ((q & 7) << 4);
    bf16x8 pa = *(const bf16x8*)(smem + 81920 + offa);
#pragma unroll
    for (int ni = 0; ni < 4; ++ni) {
      int d = ni * 16 + c16;
      int offb = (d * 512 + ks * 64 + g * 16) ^ ((d & 7) << 4);
      bf16x8 vb = *(const bf16x8*)(smem + 32768 + offb);
      oacc[ni] = __builtin_amdgcn_mfma_f32_16x16x32_bf16(pa, vb, oacc[ni],
                                                         0, 0, 0);
    }
  }

  // O re-tile: per-wave private 2KB slice of the (now dead) Qsm region.
  // oacc frag: row (within 16q) = g*4+j, col d = ni*16+c16.
  {
    char* ox = smem + 65536 + w * 2048;
#pragma unroll
    for (int ni = 0; ni < 4; ++ni)
#pragma unroll
      for (int j = 0; j < 4; ++j) {
        int row = g * 4 + j, col = ni * 16 + c16;
        int off = (row * 128 + col * 2) ^ ((row & 7) << 4);
        *(bf16*)(ox + off) = (bf16)oacc[ni][j];
      }
    asm volatile("s_waitcnt lgkmcnt(0)" ::: "memory");
#pragma unroll
    for (int it = 0; it < 2; ++it) {
      int c = it * 64 + lane;
      int row = c >> 3, ch = c & 7;
      int off = (row * 128 + ch * 16) ^ ((row & 7) << 4);
      bf16x8 v = *(const bf16x8*)(ox + off);
      *(bf16x8*)(O + ((size_t)b * 4096 + n0 + w * 16 + row) * 512 + h * 64 +
                 ch * 8) = v;
    }
  }
}

// ---------------------------------------------------------------------------
extern "C" void kernel_launch(void* const* d_in, const int* in_sizes, int n_in,
                              void* d_out, int out_size, void* d_ws,
                              size_t ws_size, hipStream_t stream) {
  const float* X = (const float*)d_in[0];
  const float* S = (const float*)d_in[1];
  const float* Wq = (const float*)d_in[2];
  const float* Wk = (const float*)d_in[3];
  const float* Wv = (const float*)d_in[4];
  const float* Wo = (const float*)d_in[5];
  const float* temp = (const float*)d_in[6];
  float* out = (float*)d_out;

  char* ws = (char*)d_ws;
  bf16* Qws = (bf16*)ws;                      // 32768*512*2 = 33,554,432 B
  bf16* Kws = (bf16*)(ws + 33554432);         //  2048*512*2 =  2,097,152 B
  bf16* Vtws = (bf16*)(ws + 35651584);        //  8*8*64*256*2 = 2,097,152 B
  bf16* Wqb = (bf16*)(ws + 37748736);         //  512*512*2 = 524,288 B each
  bf16* Wkb = (bf16*)(ws + 38273024);
  bf16* Wvb = (bf16*)(ws + 38797312);
  bf16* Wob = (bf16*)(ws + 39321600);

  // Xb/Sb scratch inside d_out (67.1 MB f32): dead before out_gemm writes.
  bf16* Xb = (bf16*)d_out;                      // 33,554,432 B
  bf16* Sb = (bf16*)((char*)d_out + 33554432);  //  2,097,152 B

  cvt_all<<<dim3(9216), dim3(256), 0, stream>>>(X, S, Wq, Wk, Wv, Wo, Xb, Sb,
                                                Wqb, Wkb, Wvb, Wob);
  proj_all<<<dim3(1152), dim3(256), 0, stream>>>(Xb, Sb, Wqb, Wkb, Wvb, Qws,
                                                 Kws, Vtws);
  attn_fused<<<dim3(2048), dim3(512), 0, stream>>>(Qws, Kws, Vtws, temp, Qws);
  out_gemm<<<dim3(1024), dim3(256), 0, stream>>>(Qws, Wob, X, out);
}

// Round 15
// 129.573 us; speedup vs baseline: 1.2149x; 1.0409x over previous
//
#include <hip/hip_runtime.h>
#include <hip/hip_bf16.h>

// MDTA (multi-head cross attention with l2-normed q/k) for MI355X.
// B=8, N=4096, Ktok=256, C=512, H=8, D=64. Inputs f32, output f32.
//
// R8 187.9 -> R9 153.1 -> R10 167.8 -> R11 151.2 -> R12 157.4 -> R13 155.0
// -> R14 134.9 (depth-3 GEMM pipeline + coalesced epilogues).
// R15: attention occupancy. QBLK=64, 4 waves, LDS 72KB (P overlays dead Ksm,
// O-retile overlays dead Qsm) -> 2 independent blocks/CU; 4-acc softmax
// reduction trees; XCD swizzle for K/V L2 locality.
//
// Pipeline: cvt_all (W,X,S->bf16) -> proj_all -> attn_fused -> out_gemm.

typedef __bf16 bf16;
typedef __attribute__((ext_vector_type(8))) __bf16 bf16x8;
typedef __attribute__((ext_vector_type(4))) float f32x4;

__device__ __forceinline__ void gload_lds16(const void* g, void* l) {
  __builtin_amdgcn_global_load_lds(
      (__attribute__((address_space(1))) void*)g,
      (__attribute__((address_space(3))) void*)l, 16, 0, 0);
}

__device__ __forceinline__ unsigned pack2(float a, float b) {
  unsigned short x = __builtin_bit_cast(unsigned short, (bf16)a);
  unsigned short y = __builtin_bit_cast(unsigned short, (bf16)b);
  return (unsigned)x | ((unsigned)y << 16);
}

// ---------------------------------------------------------------------------
// Convert X (2097152 chunks), S (131072), Wq/Wk/Wv/Wo (32768 each) to bf16.
// ---------------------------------------------------------------------------
__global__ __launch_bounds__(256) void cvt_all(
    const float* __restrict__ X, const float* __restrict__ S,
    const float* __restrict__ Wq, const float* __restrict__ Wk,
    const float* __restrict__ Wv, const float* __restrict__ Wo,
    bf16* __restrict__ Xb, bf16* __restrict__ Sb, bf16* __restrict__ Wqb,
    bf16* __restrict__ Wkb, bf16* __restrict__ Wvb, bf16* __restrict__ Wob) {
  int i = blockIdx.x * 256 + threadIdx.x;
  const float* src;
  bf16* dst;
  int r;
  if (i < 2097152) {
    src = X; dst = Xb; r = i;
  } else if (i < 2228224) {
    src = S; dst = Sb; r = i - 2097152;
  } else {
    int j = i - 2228224;
    int w = j >> 15;
    r = j & 32767;
    src = (w == 0) ? Wq : (w == 1) ? Wk : (w == 2) ? Wv : Wo;
    dst = (w == 0) ? Wqb : (w == 1) ? Wkb : (w == 2) ? Wvb : Wob;
  }
  float4 a = *(const float4*)(src + (size_t)r * 8);
  float4 b = *(const float4*)(src + (size_t)r * 8 + 4);
  uint4 v;
  v.x = pack2(a.x, a.y);
  v.y = pack2(a.z, a.w);
  v.z = pack2(b.x, b.y);
  v.w = pack2(b.z, b.w);
  *(uint4*)(dst + (size_t)r * 8) = v;
}

// ---------------------------------------------------------------------------
// Fused Q/K/V projection, all-bf16. 128x128 tile, BK=32, 16 stages,
// depth-3 gload_lds pipeline (vmcnt(8) steady state, loads span barriers).
// Epilogue: l2norm -> per-wave swizzled LDS re-tile -> bf16x8 stores.
// ---------------------------------------------------------------------------
__global__ __launch_bounds__(256) void proj_all(
    const bf16* __restrict__ Xb, const bf16* __restrict__ Sb,
    const bf16* __restrict__ Wqb, const bf16* __restrict__ Wkb,
    const bf16* __restrict__ Wvb, bf16* __restrict__ Q,
    bf16* __restrict__ Kn, bf16* __restrict__ Vt) {
  __shared__ __align__(16) char smem[49152];  // 3x(As 8KB + Bs 8KB)

  const int lg = (blockIdx.x & 7) * 144 + (blockIdx.x >> 3);

  const bf16* A;
  const bf16* W;
  int m0, kind;  // 0=Q, 1=K, 2=V
  if (lg < 1024) {
    kind = 0; A = Xb; W = Wqb; m0 = (lg >> 2) * 128;
  } else if (lg < 1088) {
    kind = 1; A = Sb; W = Wkb; m0 = ((lg - 1024) >> 2) * 128;
  } else {
    kind = 2; A = Sb; W = Wvb; m0 = ((lg - 1088) >> 2) * 128;
  }
  const int n0 = (lg & 3) * 128;

  const int tid = threadIdx.x;
  const int wid = tid >> 6, lane = tid & 63;
  const int wr = wid >> 1, wc = wid & 1;
  const int g = lane >> 4, c16 = lane & 15;
  const int r0 = tid >> 2, cc0 = tid & 3;
  const int r1 = (256 + tid) >> 2, cc1 = tid & 3;
  const int dst0 = (tid & ~63) * 16, dst1 = (256 + (tid & ~63)) * 16;

  f32x4 acc[4][4] = {};

#define PSTAGE(kb, buf)                                                     \
  {                                                                         \
    char* as = smem + (buf) * 8192;                                         \
    char* bs = smem + 24576 + (buf) * 8192;                                 \
    gload_lds16(A + (size_t)(m0 + r0) * 512 + (kb) + cc0 * 8, as + dst0);   \
    gload_lds16(A + (size_t)(m0 + r1) * 512 + (kb) + cc1 * 8, as + dst1);   \
    gload_lds16(W + (size_t)(n0 + r0) * 512 + (kb) + cc0 * 8, bs + dst0);   \
    gload_lds16(W + (size_t)(n0 + r1) * 512 + (kb) + cc1 * 8, bs + dst1);   \
  }

#define PCOMPUTE(buf)                                                       \
  {                                                                         \
    const bf16* as = (const bf16*)(smem + (buf) * 8192);                    \
    const bf16* bs = (const bf16*)(smem + 24576 + (buf) * 8192);            \
    bf16x8 af[4], bfr[4];                                                   \
    _Pragma("unroll") for (int mi = 0; mi < 4; ++mi) af[mi] =               \
        *(const bf16x8*)(as + (wr * 64 + mi * 16 + c16) * 32 + g * 8);      \
    _Pragma("unroll") for (int ni = 0; ni < 4; ++ni) bfr[ni] =              \
        *(const bf16x8*)(bs + (wc * 64 + ni * 16 + c16) * 32 + g * 8);      \
    _Pragma("unroll") for (int mi = 0; mi < 4; ++mi)                        \
        _Pragma("unroll") for (int ni = 0; ni < 4; ++ni) acc[mi][ni] =      \
            __builtin_amdgcn_mfma_f32_16x16x32_bf16(af[mi], bfr[ni],        \
                                                    acc[mi][ni], 0, 0, 0);  \
  }

  PSTAGE(0, 0);
  PSTAGE(32, 1);
  int bufc = 0;
  for (int t = 0; t < 14; ++t) {
    int bufn = bufc + 2;
    if (bufn >= 3) bufn -= 3;
    PSTAGE((t + 2) * 32, bufn);
    asm volatile("s_waitcnt vmcnt(8)" ::: "memory");
    __builtin_amdgcn_s_barrier();
    PCOMPUTE(bufc);
    __builtin_amdgcn_s_barrier();
    if (++bufc == 3) bufc = 0;
  }
  asm volatile("s_waitcnt vmcnt(4)" ::: "memory");
  __builtin_amdgcn_s_barrier();
  PCOMPUTE(bufc);
  __builtin_amdgcn_s_barrier();
  if (++bufc == 3) bufc = 0;
  asm volatile("s_waitcnt vmcnt(0)" ::: "memory");
  __builtin_amdgcn_s_barrier();
  PCOMPUTE(bufc);

  __syncthreads();  // release K-loop LDS for epilogue re-tile

  // ---- epilogue. C/D frag: col = lane&15, row = (lane>>4)*4 + j   [m89]
  if (kind != 2) {
    bf16* C = (kind == 0) ? Q : Kn;
    char* eps = smem + wid * 8192;  // wave-private 64x64 bf16 tile
#pragma unroll
    for (int mi = 0; mi < 4; ++mi) {
      float ss[4];
#pragma unroll
      for (int j = 0; j < 4; ++j) {
        float s = 0.f;
#pragma unroll
        for (int ni = 0; ni < 4; ++ni) {
          float v = acc[mi][ni][j];
          s += v * v;
        }
        ss[j] = s;
      }
#pragma unroll
      for (int msk = 1; msk < 16; msk <<= 1)
#pragma unroll
        for (int j = 0; j < 4; ++j) ss[j] += __shfl_xor(ss[j], msk, 64);
      float inv[4];
#pragma unroll
      for (int j = 0; j < 4; ++j) inv[j] = rsqrtf(fmaxf(ss[j], 1e-24f));
#pragma unroll
      for (int ni = 0; ni < 4; ++ni)
#pragma unroll
        for (int j = 0; j < 4; ++j) {
          int row = mi * 16 + g * 4 + j, col = ni * 16 + c16;
          int off = (row * 128 + col * 2) ^ ((row & 7) << 4);
          *(bf16*)(eps + off) = (bf16)(acc[mi][ni][j] * inv[j]);
        }
    }
    asm volatile("s_waitcnt lgkmcnt(0)" ::: "memory");
#pragma unroll
    for (int it = 0; it < 8; ++it) {
      int c = it * 64 + lane;
      int row = c >> 3, ch = c & 7;
      int off = (row * 128 + ch * 16) ^ ((row & 7) << 4);
      bf16x8 v = *(const bf16x8*)(eps + off);
      *(bf16x8*)(C + (size_t)(m0 + wr * 64 + row) * 512 + n0 + wc * 64 +
                 ch * 8) = v;
    }
  } else {
    // transposed store into Vt[b][h][d][t] (M=2048): 8B stores, small.
#pragma unroll
    for (int mi = 0; mi < 4; ++mi) {
      int m = m0 + wr * 64 + mi * 16 + g * 4;  // +j
      int b = m >> 8, tt = m & 255;
#pragma unroll
      for (int ni = 0; ni < 4; ++ni) {
        int col = n0 + wc * 64 + ni * 16 + c16;
        int h = col >> 6, d = col & 63;
        uint2 v;
        v.x = pack2(acc[mi][ni][0], acc[mi][ni][1]);
        v.y = pack2(acc[mi][ni][2], acc[mi][ni][3]);
        *(uint2*)(Vt + ((size_t)((b * 8 + h) * 64 + d) * 256 + tt)) = v;
      }
    }
  }
#undef PSTAGE
#undef PCOMPUTE
}

// ---------------------------------------------------------------------------
// out = X + O @ Wo^T, f32 output. Depth-3 pipeline + f32x4 re-tiled epilogue.
// ---------------------------------------------------------------------------
__global__ __launch_bounds__(256) void out_gemm(
    const bf16* __restrict__ O, const bf16* __restrict__ Wob,
    const float* __restrict__ Xres, float* __restrict__ out) {
  __shared__ __align__(16) char smem[49152];

  const int lg = (blockIdx.x & 7) * 128 + (blockIdx.x >> 3);  // XCD swizzle
  const int m0 = (lg >> 2) * 128, n0 = (lg & 3) * 128;

  const int tid = threadIdx.x;
  const int wid = tid >> 6, lane = tid & 63;
  const int wr = wid >> 1, wc = wid & 1;
  const int g = lane >> 4, c16 = lane & 15;
  const int r0 = tid >> 2, cc0 = tid & 3;
  const int r1 = (256 + tid) >> 2, cc1 = tid & 3;
  const int dst0 = (tid & ~63) * 16, dst1 = (256 + (tid & ~63)) * 16;

  f32x4 acc[4][4] = {};

#define OSTAGE(kb, buf)                                                      \
  {                                                                          \
    char* as = smem + (buf) * 8192;                                          \
    char* bs = smem + 24576 + (buf) * 8192;                                  \
    gload_lds16(O + (size_t)(m0 + r0) * 512 + (kb) + cc0 * 8, as + dst0);    \
    gload_lds16(O + (size_t)(m0 + r1) * 512 + (kb) + cc1 * 8, as + dst1);    \
    gload_lds16(Wob + (size_t)(n0 + r0) * 512 + (kb) + cc0 * 8, bs + dst0);  \
    gload_lds16(Wob + (size_t)(n0 + r1) * 512 + (kb) + cc1 * 8, bs + dst1);  \
  }

#define OCOMPUTE(buf)                                                       \
  {                                                                         \
    const bf16* as = (const bf16*)(smem + (buf) * 8192);                    \
    const bf16* bs = (const bf16*)(smem + 24576 + (buf) * 8192);            \
    bf16x8 af[4], bfr[4];                                                   \
    _Pragma("unroll") for (int mi = 0; mi < 4; ++mi) af[mi] =               \
        *(const bf16x8*)(as + (wr * 64 + mi * 16 + c16) * 32 + g * 8);      \
    _Pragma("unroll") for (int ni = 0; ni < 4; ++ni) bfr[ni] =              \
        *(const bf16x8*)(bs + (wc * 64 + ni * 16 + c16) * 32 + g * 8);      \
    _Pragma("unroll") for (int mi = 0; mi < 4; ++mi)                        \
        _Pragma("unroll") for (int ni = 0; ni < 4; ++ni) acc[mi][ni] =      \
            __builtin_amdgcn_mfma_f32_16x16x32_bf16(af[mi], bfr[ni],        \
                                                    acc[mi][ni], 0, 0, 0);  \
  }

  OSTAGE(0, 0);
  OSTAGE(32, 1);
  int bufc = 0;
  for (int t = 0; t < 14; ++t) {
    int bufn = bufc + 2;
    if (bufn >= 3) bufn -= 3;
    OSTAGE((t + 2) * 32, bufn);
    asm volatile("s_waitcnt vmcnt(8)" ::: "memory");
    __builtin_amdgcn_s_barrier();
    OCOMPUTE(bufc);
    __builtin_amdgcn_s_barrier();
    if (++bufc == 3) bufc = 0;
  }
  asm volatile("s_waitcnt vmcnt(4)" ::: "memory");
  __builtin_amdgcn_s_barrier();
  OCOMPUTE(bufc);
  __builtin_amdgcn_s_barrier();
  if (++bufc == 3) bufc = 0;
  asm volatile("s_waitcnt vmcnt(0)" ::: "memory");
  __builtin_amdgcn_s_barrier();
  OCOMPUTE(bufc);

  __syncthreads();  // release K-loop LDS for f32 re-tile

  // Epilogue: 2 passes x (32 rows x 64 cols f32) per wave, swizzled LDS,
  // then float4 X-load + add + float4 store (full-line writes).
  char* eps = smem + wid * 8192;
#pragma unroll
  for (int p = 0; p < 2; ++p) {
#pragma unroll
    for (int mm = 0; mm < 2; ++mm)
#pragma unroll
      for (int ni = 0; ni < 4; ++ni)
#pragma unroll
        for (int j = 0; j < 4; ++j) {
          int row = mm * 16 + g * 4 + j, col = ni * 16 + c16;
          int off = (row * 256 + col * 4) ^ ((row & 7) << 4);
          *(float*)(eps + off) = acc[p * 2 + mm][ni][j];
        }
    asm volatile("s_waitcnt lgkmcnt(0)" ::: "memory");
#pragma unroll
    for (int it = 0; it < 8; ++it) {
      int c = it * 64 + lane;
      int row = c >> 4, ch = c & 15;
      int off = (row * 256 + ch * 16) ^ ((row & 7) << 4);
      float4 v = *(const float4*)(eps + off);
      size_t gr = (size_t)(m0 + wr * 64 + p * 32 + row) * 512 + n0 +
                  wc * 64 + ch * 4;
      float4 x = *(const float4*)(Xres + gr);
      v.x += x.x;
      v.y += x.y;
      v.z += x.z;
      v.w += x.w;
      *(float4*)(out + gr) = v;
    }
    asm volatile("s_waitcnt lgkmcnt(0)" ::: "memory");
  }
#undef OSTAGE
#undef OCOMPUTE
}

// ---------------------------------------------------------------------------
// Fused attention. Block = (b, h, 64 q-rows), 256 thr = 4 waves, 72 KB LDS
// -> 2 independent blocks/CU. Wave w owns q in [16w,16w+16).
//   [0,32768)     Ksm [256t][64d] swz   -> overlaid by Psm [64q][256k] swz
//   [32768,65536) Vsm [64d][256t] swz
//   [65536,73728) Qsm [64q][64d] swz    -> per-wave O re-tile (2KB/wave)
// ---------------------------------------------------------------------------
__global__ __launch_bounds__(256) void attn_fused(
    const bf16* __restrict__ Qn, const bf16* __restrict__ Kn,
    const bf16* __restrict__ Vt, const float* __restrict__ temp,
    bf16* __restrict__ O) {
  __shared__ __align__(16) char smem[73728];

  const int tid = threadIdx.x;
  const int w = tid >> 6, lane = tid & 63;
  const int g = lane >> 4, c16 = lane & 15;
  // XCD swizzle: 4096 = 8 XCDs x 512; blocks sharing (b,h) -> same XCD L2.
  const int lg = (blockIdx.x & 7) * 512 + (blockIdx.x >> 3);
  const int nt = lg & 63, h = (lg >> 6) & 7, b = lg >> 9;
  const int n0 = nt * 64;

  // ---- stage K, V^T, Q (reg-staged, swizzled LDS writes)
  {
    const bf16* Ksrc = Kn + ((size_t)b * 256) * 512 + h * 64;
#pragma unroll
    for (int it = 0; it < 8; ++it) {
      int c = it * 256 + tid;  // 2048 chunks of 16B
      int t = c >> 3, dc = c & 7;
      int4 v = *(const int4*)(Ksrc + (size_t)t * 512 + dc * 8);
      int off = (t * 128 + dc * 16) ^ ((t & 7) << 4);
      *(int4*)(smem + off) = v;
    }
    const bf16* Vsrc = Vt + (size_t)((b * 8 + h) * 64) * 256;
#pragma unroll
    for (int it = 0; it < 8; ++it) {
      int c = it * 256 + tid;
      int d = c >> 5, tc = c & 31;
      int4 v = *(const int4*)(Vsrc + (size_t)d * 256 + tc * 8);
      int off = (d * 512 + tc * 16) ^ ((d & 7) << 4);
      *(int4*)(smem + 32768 + off) = v;
    }
    const bf16* Qsrc = Qn + ((size_t)b * 4096 + n0) * 512 + h * 64;
#pragma unroll
    for (int it = 0; it < 2; ++it) {
      int c = it * 256 + tid;  // 512 chunks
      int q = c >> 3, dc = c & 7;
      int4 v = *(const int4*)(Qsrc + (size_t)q * 512 + dc * 8);
      int off = 65536 + ((q * 128 + dc * 16) ^ ((q & 7) << 4));
      *(int4*)(smem + off) = v;
    }
  }
  __syncthreads();

  const int q = w * 16 + c16;  // this lane's q row (0..63)

  // ---- S^T = mfma(K, Q^T): lane holds P[q][k], k = mi*16 + g*4 + j
  f32x4 sacc[16] = {};
  bf16x8 qf[2];
#pragma unroll
  for (int s = 0; s < 2; ++s) {
    int off = 65536 + ((q * 128 + s * 64 + g * 16) ^ ((q & 7) << 4));
    qf[s] = *(const bf16x8*)(smem + off);
  }
#pragma unroll
  for (int mi = 0; mi < 16; ++mi) {
#pragma unroll
    for (int s = 0; s < 2; ++s) {
      int t = mi * 16 + c16;
      int off = (t * 128 + s * 64 + g * 16) ^ ((t & 7) << 4);
      bf16x8 kf = *(const bf16x8*)(smem + off);
      sacc[mi] = __builtin_amdgcn_mfma_f32_16x16x32_bf16(kf, qf[s], sacc[mi],
                                                         0, 0, 0);
    }
  }

  // ---- softmax over k: 4 parallel chains + tree, then shfl(16,32)
  float tv = temp[h];
  float mx4[4] = {-1e30f, -1e30f, -1e30f, -1e30f};
#pragma unroll
  for (int mi = 0; mi < 16; ++mi)
#pragma unroll
    for (int j = 0; j < 4; ++j) {
      sacc[mi][j] *= tv;
      mx4[j] = fmaxf(mx4[j], sacc[mi][j]);
    }
  float mx = fmaxf(fmaxf(mx4[0], mx4[1]), fmaxf(mx4[2], mx4[3]));
  mx = fmaxf(mx, __shfl_xor(mx, 16, 64));
  mx = fmaxf(mx, __shfl_xor(mx, 32, 64));
  float sm4[4] = {0.f, 0.f, 0.f, 0.f};
#pragma unroll
  for (int mi = 0; mi < 16; ++mi)
#pragma unroll
    for (int j = 0; j < 4; ++j) {
      float p = __expf(sacc[mi][j] - mx);
      sacc[mi][j] = p;
      sm4[j] += p;
    }
  float sum = (sm4[0] + sm4[1]) + (sm4[2] + sm4[3]);
  sum += __shfl_xor(sum, 16, 64);
  sum += __shfl_xor(sum, 32, 64);
  float inv = 1.0f / sum;

  __syncthreads();  // K reads done by all waves; Ksm region now dead

  // ---- P[q][k] -> LDS overlay at base 0 (bf16, swizzled)
#pragma unroll
  for (int mi = 0; mi < 16; ++mi) {
    uint2 v;
    v.x = pack2(sacc[mi][0] * inv, sacc[mi][1] * inv);
    v.y = pack2(sacc[mi][2] * inv, sacc[mi][3] * inv);
    int off = (q * 512 + mi * 32 + g * 8) ^ ((q & 7) << 4);
    *(uint2*)(smem + off) = v;
  }
  __syncthreads();

  // ---- O = P @ V
  f32x4 oacc[4] = {};
#pragma unroll
  for (int ks = 0; ks < 8; ++ks) {
    int offa = (q * 512 + ks * 64 + g * 16) ^ ((q & 7) << 4);
    bf16x8 pa = *(const bf16x8*)(smem + offa);
#pragma unroll
    for (int ni = 0; ni < 4; ++ni) {
      int d = ni * 16 + c16;
      int offb = 32768 + ((d * 512 + ks * 64 + g * 16) ^ ((d & 7) << 4));
      bf16x8 vb = *(const bf16x8*)(smem + offb);
      oacc[ni] = __builtin_amdgcn_mfma_f32_16x16x32_bf16(pa, vb, oacc[ni],
                                                         0, 0, 0);
    }
  }

  // ---- O re-tile in dead wave-private Qsm slice -> bf16x8 stores
  {
    char* ox = smem + 65536 + w * 2048;
#pragma unroll
    for (int ni = 0; ni < 4; ++ni)
#pragma unroll
      for (int j = 0; j < 4; ++j) {
        int row = g * 4 + j, col = ni * 16 + c16;
        int off = (row * 128 + col * 2) ^ ((row & 7) << 4);
        *(bf16*)(ox + off) = (bf16)oacc[ni][j];
      }
    asm volatile("s_waitcnt lgkmcnt(0)" ::: "memory");
#pragma unroll
    for (int it = 0; it < 2; ++it) {
      int c = it * 64 + lane;
      int row = c >> 3, ch = c & 7;
      int off = (row * 128 + ch * 16) ^ ((row & 7) << 4);
      bf16x8 v = *(const bf16x8*)(ox + off);
      *(bf16x8*)(O + ((size_t)b * 4096 + n0 + w * 16 + row) * 512 + h * 64 +
                 ch * 8) = v;
    }
  }
}

// ---------------------------------------------------------------------------
extern "C" void kernel_launch(void* const* d_in, const int* in_sizes, int n_in,
                              void* d_out, int out_size, void* d_ws,
                              size_t ws_size, hipStream_t stream) {
  const float* X = (const float*)d_in[0];
  const float* S = (const float*)d_in[1];
  const float* Wq = (const float*)d_in[2];
  const float* Wk = (const float*)d_in[3];
  const float* Wv = (const float*)d_in[4];
  const float* Wo = (const float*)d_in[5];
  const float* temp = (const float*)d_in[6];
  float* out = (float*)d_out;

  char* ws = (char*)d_ws;
  bf16* Qws = (bf16*)ws;                      // 32768*512*2 = 33,554,432 B
  bf16* Kws = (bf16*)(ws + 33554432);         //  2048*512*2 =  2,097,152 B
  bf16* Vtws = (bf16*)(ws + 35651584);        //  8*8*64*256*2 = 2,097,152 B
  bf16* Wqb = (bf16*)(ws + 37748736);         //  512*512*2 = 524,288 B each
  bf16* Wkb = (bf16*)(ws + 38273024);
  bf16* Wvb = (bf16*)(ws + 38797312);
  bf16* Wob = (bf16*)(ws + 39321600);

  // Xb/Sb scratch inside d_out (67.1 MB f32): dead before out_gemm writes.
  bf16* Xb = (bf16*)d_out;                      // 33,554,432 B
  bf16* Sb = (bf16*)((char*)d_out + 33554432);  //  2,097,152 B

  cvt_all<<<dim3(9216), dim3(256), 0, stream>>>(X, S, Wq, Wk, Wv, Wo, Xb, Sb,
                                                Wqb, Wkb, Wvb, Wob);
  proj_all<<<dim3(1152), dim3(256), 0, stream>>>(Xb, Sb, Wqb, Wkb, Wvb, Qws,
                                                 Kws, Vtws);
  attn_fused<<<dim3(4096), dim3(256), 0, stream>>>(Qws, Kws, Vtws, temp, Qws);
  out_gemm<<<dim3(1024), dim3(256), 0, stream>>>(Qws, Wob, X, out);
}

// Round 16
// 127.639 us; speedup vs baseline: 1.2333x; 1.0152x over previous
//
#include <hip/hip_runtime.h>
#include <hip/hip_bf16.h>

// MDTA (multi-head cross attention with l2-normed q/k) for MI355X.
// B=8, N=4096, Ktok=256, C=512, H=8, D=64. Inputs f32, output f32.
//
// R8 187.9 -> R9 153.1 -> R10 167.8 -> R11 151.2 -> R12 157.4 -> R13 155.0
// -> R14 134.9 -> R15 129.6.
// R16 (attn VALU diet): gload_lds staging w/ pre-swizzled global source
// (kills staging VALU + swizzled-ds_write bank conflicts), temperature*log2e
// folded into Q at proj epilogue, exp2-based softmax, 1/sum deferred to oacc,
// Q direct-to-reg, P wave-private (one barrier fewer), LDS 64KB.
//
// Pipeline: cvt_all (W,X,S->bf16) -> proj_all -> attn_fused -> out_gemm.

typedef __bf16 bf16;
typedef __attribute__((ext_vector_type(8))) __bf16 bf16x8;
typedef __attribute__((ext_vector_type(4))) float f32x4;

#if __has_builtin(__builtin_amdgcn_exp2f)
#define EXP2(x) __builtin_amdgcn_exp2f(x)
#else
#define EXP2(x) exp2f(x)
#endif

__device__ __forceinline__ void gload_lds16(const void* g, void* l) {
  __builtin_amdgcn_global_load_lds(
      (__attribute__((address_space(1))) void*)g,
      (__attribute__((address_space(3))) void*)l, 16, 0, 0);
}

__device__ __forceinline__ unsigned pack2(float a, float b) {
  unsigned short x = __builtin_bit_cast(unsigned short, (bf16)a);
  unsigned short y = __builtin_bit_cast(unsigned short, (bf16)b);
  return (unsigned)x | ((unsigned)y << 16);
}

// ---------------------------------------------------------------------------
// Convert X (2097152 chunks), S (131072), Wq/Wk/Wv/Wo (32768 each) to bf16.
// ---------------------------------------------------------------------------
__global__ __launch_bounds__(256) void cvt_all(
    const float* __restrict__ X, const float* __restrict__ S,
    const float* __restrict__ Wq, const float* __restrict__ Wk,
    const float* __restrict__ Wv, const float* __restrict__ Wo,
    bf16* __restrict__ Xb, bf16* __restrict__ Sb, bf16* __restrict__ Wqb,
    bf16* __restrict__ Wkb, bf16* __restrict__ Wvb, bf16* __restrict__ Wob) {
  int i = blockIdx.x * 256 + threadIdx.x;
  const float* src;
  bf16* dst;
  int r;
  if (i < 2097152) {
    src = X; dst = Xb; r = i;
  } else if (i < 2228224) {
    src = S; dst = Sb; r = i - 2097152;
  } else {
    int j = i - 2228224;
    int w = j >> 15;
    r = j & 32767;
    src = (w == 0) ? Wq : (w == 1) ? Wk : (w == 2) ? Wv : Wo;
    dst = (w == 0) ? Wqb : (w == 1) ? Wkb : (w == 2) ? Wvb : Wob;
  }
  float4 a = *(const float4*)(src + (size_t)r * 8);
  float4 b = *(const float4*)(src + (size_t)r * 8 + 4);
  uint4 v;
  v.x = pack2(a.x, a.y);
  v.y = pack2(a.z, a.w);
  v.z = pack2(b.x, b.y);
  v.w = pack2(b.z, b.w);
  *(uint4*)(dst + (size_t)r * 8) = v;
}

// ---------------------------------------------------------------------------
// Fused Q/K/V projection, all-bf16. 128x128 tile, BK=32, 16 stages,
// depth-3 gload_lds pipeline. Epilogue: l2norm (Q additionally scaled by
// temp[h]*log2e for the attn exp2 path) -> swizzled LDS re-tile -> bf16x8.
// ---------------------------------------------------------------------------
__global__ __launch_bounds__(256) void proj_all(
    const bf16* __restrict__ Xb, const bf16* __restrict__ Sb,
    const bf16* __restrict__ Wqb, const bf16* __restrict__ Wkb,
    const bf16* __restrict__ Wvb, const float* __restrict__ temp,
    bf16* __restrict__ Q, bf16* __restrict__ Kn, bf16* __restrict__ Vt) {
  __shared__ __align__(16) char smem[49152];  // 3x(As 8KB + Bs 8KB)

  const int lg = (blockIdx.x & 7) * 144 + (blockIdx.x >> 3);

  const bf16* A;
  const bf16* W;
  int m0, kind;  // 0=Q, 1=K, 2=V
  if (lg < 1024) {
    kind = 0; A = Xb; W = Wqb; m0 = (lg >> 2) * 128;
  } else if (lg < 1088) {
    kind = 1; A = Sb; W = Wkb; m0 = ((lg - 1024) >> 2) * 128;
  } else {
    kind = 2; A = Sb; W = Wvb; m0 = ((lg - 1088) >> 2) * 128;
  }
  const int n0 = (lg & 3) * 128;

  const int tid = threadIdx.x;
  const int wid = tid >> 6, lane = tid & 63;
  const int wr = wid >> 1, wc = wid & 1;
  const int g = lane >> 4, c16 = lane & 15;
  const int r0 = tid >> 2, cc0 = tid & 3;
  const int r1 = (256 + tid) >> 2, cc1 = tid & 3;
  const int dst0 = (tid & ~63) * 16, dst1 = (256 + (tid & ~63)) * 16;

  f32x4 acc[4][4] = {};

#define PSTAGE(kb, buf)                                                     \
  {                                                                         \
    char* as = smem + (buf) * 8192;                                         \
    char* bs = smem + 24576 + (buf) * 8192;                                 \
    gload_lds16(A + (size_t)(m0 + r0) * 512 + (kb) + cc0 * 8, as + dst0);   \
    gload_lds16(A + (size_t)(m0 + r1) * 512 + (kb) + cc1 * 8, as + dst1);   \
    gload_lds16(W + (size_t)(n0 + r0) * 512 + (kb) + cc0 * 8, bs + dst0);   \
    gload_lds16(W + (size_t)(n0 + r1) * 512 + (kb) + cc1 * 8, bs + dst1);   \
  }

#define PCOMPUTE(buf)                                                       \
  {                                                                         \
    const bf16* as = (const bf16*)(smem + (buf) * 8192);                    \
    const bf16* bs = (const bf16*)(smem + 24576 + (buf) * 8192);            \
    bf16x8 af[4], bfr[4];                                                   \
    _Pragma("unroll") for (int mi = 0; mi < 4; ++mi) af[mi] =               \
        *(const bf16x8*)(as + (wr * 64 + mi * 16 + c16) * 32 + g * 8);      \
    _Pragma("unroll") for (int ni = 0; ni < 4; ++ni) bfr[ni] =              \
        *(const bf16x8*)(bs + (wc * 64 + ni * 16 + c16) * 32 + g * 8);      \
    _Pragma("unroll") for (int mi = 0; mi < 4; ++mi)                        \
        _Pragma("unroll") for (int ni = 0; ni < 4; ++ni) acc[mi][ni] =      \
            __builtin_amdgcn_mfma_f32_16x16x32_bf16(af[mi], bfr[ni],        \
                                                    acc[mi][ni], 0, 0, 0);  \
  }

  PSTAGE(0, 0);
  PSTAGE(32, 1);
  int bufc = 0;
  for (int t = 0; t < 14; ++t) {
    int bufn = bufc + 2;
    if (bufn >= 3) bufn -= 3;
    PSTAGE((t + 2) * 32, bufn);
    asm volatile("s_waitcnt vmcnt(8)" ::: "memory");
    __builtin_amdgcn_s_barrier();
    PCOMPUTE(bufc);
    __builtin_amdgcn_s_barrier();
    if (++bufc == 3) bufc = 0;
  }
  asm volatile("s_waitcnt vmcnt(4)" ::: "memory");
  __builtin_amdgcn_s_barrier();
  PCOMPUTE(bufc);
  __builtin_amdgcn_s_barrier();
  if (++bufc == 3) bufc = 0;
  asm volatile("s_waitcnt vmcnt(0)" ::: "memory");
  __builtin_amdgcn_s_barrier();
  PCOMPUTE(bufc);

  __syncthreads();  // release K-loop LDS for epilogue re-tile

  // ---- epilogue. C/D frag: col = lane&15, row = (lane>>4)*4 + j   [m89]
  if (kind != 2) {
    bf16* C = (kind == 0) ? Q : Kn;
    // Q additionally scaled by temp[h]*log2(e): attn uses exp2(s - max).
    const float sc =
        (kind == 0) ? temp[(n0 + wc * 64) >> 6] * 1.44269504088896f : 1.0f;
    char* eps = smem + wid * 8192;  // wave-private 64x64 bf16 tile
#pragma unroll
    for (int mi = 0; mi < 4; ++mi) {
      float ss[4];
#pragma unroll
      for (int j = 0; j < 4; ++j) {
        float s = 0.f;
#pragma unroll
        for (int ni = 0; ni < 4; ++ni) {
          float v = acc[mi][ni][j];
          s += v * v;
        }
        ss[j] = s;
      }
#pragma unroll
      for (int msk = 1; msk < 16; msk <<= 1)
#pragma unroll
        for (int j = 0; j < 4; ++j) ss[j] += __shfl_xor(ss[j], msk, 64);
      float inv[4];
#pragma unroll
      for (int j = 0; j < 4; ++j)
        inv[j] = rsqrtf(fmaxf(ss[j], 1e-24f)) * sc;
#pragma unroll
      for (int ni = 0; ni < 4; ++ni)
#pragma unroll
        for (int j = 0; j < 4; ++j) {
          int row = mi * 16 + g * 4 + j, col = ni * 16 + c16;
          int off = (row * 128 + col * 2) ^ ((row & 7) << 4);
          *(bf16*)(eps + off) = (bf16)(acc[mi][ni][j] * inv[j]);
        }
    }
    asm volatile("s_waitcnt lgkmcnt(0)" ::: "memory");
#pragma unroll
    for (int it = 0; it < 8; ++it) {
      int c = it * 64 + lane;
      int row = c >> 3, ch = c & 7;
      int off = (row * 128 + ch * 16) ^ ((row & 7) << 4);
      bf16x8 v = *(const bf16x8*)(eps + off);
      *(bf16x8*)(C + (size_t)(m0 + wr * 64 + row) * 512 + n0 + wc * 64 +
                 ch * 8) = v;
    }
  } else {
    // transposed store into Vt[b][h][d][t] (M=2048): 8B stores, small.
#pragma unroll
    for (int mi = 0; mi < 4; ++mi) {
      int m = m0 + wr * 64 + mi * 16 + g * 4;  // +j
      int b = m >> 8, tt = m & 255;
#pragma unroll
      for (int ni = 0; ni < 4; ++ni) {
        int col = n0 + wc * 64 + ni * 16 + c16;
        int h = col >> 6, d = col & 63;
        uint2 v;
        v.x = pack2(acc[mi][ni][0], acc[mi][ni][1]);
        v.y = pack2(acc[mi][ni][2], acc[mi][ni][3]);
        *(uint2*)(Vt + ((size_t)((b * 8 + h) * 64 + d) * 256 + tt)) = v;
      }
    }
  }
#undef PSTAGE
#undef PCOMPUTE
}

// ---------------------------------------------------------------------------
// out = X + O @ Wo^T, f32 output. Depth-3 pipeline + f32x4 re-tiled epilogue.
// ---------------------------------------------------------------------------
__global__ __launch_bounds__(256) void out_gemm(
    const bf16* __restrict__ O, const bf16* __restrict__ Wob,
    const float* __restrict__ Xres, float* __restrict__ out) {
  __shared__ __align__(16) char smem[49152];

  const int lg = (blockIdx.x & 7) * 128 + (blockIdx.x >> 3);  // XCD swizzle
  const int m0 = (lg >> 2) * 128, n0 = (lg & 3) * 128;

  const int tid = threadIdx.x;
  const int wid = tid >> 6, lane = tid & 63;
  const int wr = wid >> 1, wc = wid & 1;
  const int g = lane >> 4, c16 = lane & 15;
  const int r0 = tid >> 2, cc0 = tid & 3;
  const int r1 = (256 + tid) >> 2, cc1 = tid & 3;
  const int dst0 = (tid & ~63) * 16, dst1 = (256 + (tid & ~63)) * 16;

  f32x4 acc[4][4] = {};

#define OSTAGE(kb, buf)                                                      \
  {                                                                          \
    char* as = smem + (buf) * 8192;                                          \
    char* bs = smem + 24576 + (buf) * 8192;                                  \
    gload_lds16(O + (size_t)(m0 + r0) * 512 + (kb) + cc0 * 8, as + dst0);    \
    gload_lds16(O + (size_t)(m0 + r1) * 512 + (kb) + cc1 * 8, as + dst1);    \
    gload_lds16(Wob + (size_t)(n0 + r0) * 512 + (kb) + cc0 * 8, bs + dst0);  \
    gload_lds16(Wob + (size_t)(n0 + r1) * 512 + (kb) + cc1 * 8, bs + dst1);  \
  }

#define OCOMPUTE(buf)                                                       \
  {                                                                         \
    const bf16* as = (const bf16*)(smem + (buf) * 8192);                    \
    const bf16* bs = (const bf16*)(smem + 24576 + (buf) * 8192);            \
    bf16x8 af[4], bfr[4];                                                   \
    _Pragma("unroll") for (int mi = 0; mi < 4; ++mi) af[mi] =               \
        *(const bf16x8*)(as + (wr * 64 + mi * 16 + c16) * 32 + g * 8);      \
    _Pragma("unroll") for (int ni = 0; ni < 4; ++ni) bfr[ni] =              \
        *(const bf16x8*)(bs + (wc * 64 + ni * 16 + c16) * 32 + g * 8);      \
    _Pragma("unroll") for (int mi = 0; mi < 4; ++mi)                        \
        _Pragma("unroll") for (int ni = 0; ni < 4; ++ni) acc[mi][ni] =      \
            __builtin_amdgcn_mfma_f32_16x16x32_bf16(af[mi], bfr[ni],        \
                                                    acc[mi][ni], 0, 0, 0);  \
  }

  OSTAGE(0, 0);
  OSTAGE(32, 1);
  int bufc = 0;
  for (int t = 0; t < 14; ++t) {
    int bufn = bufc + 2;
    if (bufn >= 3) bufn -= 3;
    OSTAGE((t + 2) * 32, bufn);
    asm volatile("s_waitcnt vmcnt(8)" ::: "memory");
    __builtin_amdgcn_s_barrier();
    OCOMPUTE(bufc);
    __builtin_amdgcn_s_barrier();
    if (++bufc == 3) bufc = 0;
  }
  asm volatile("s_waitcnt vmcnt(4)" ::: "memory");
  __builtin_amdgcn_s_barrier();
  OCOMPUTE(bufc);
  __builtin_amdgcn_s_barrier();
  if (++bufc == 3) bufc = 0;
  asm volatile("s_waitcnt vmcnt(0)" ::: "memory");
  __builtin_amdgcn_s_barrier();
  OCOMPUTE(bufc);

  __syncthreads();  // release K-loop LDS for f32 re-tile

  // Epilogue: 2 passes x (32 rows x 64 cols f32) per wave, swizzled LDS,
  // then float4 X-load + add + float4 store (full-line writes).
  char* eps = smem + wid * 8192;
#pragma unroll
  for (int p = 0; p < 2; ++p) {
#pragma unroll
    for (int mm = 0; mm < 2; ++mm)
#pragma unroll
      for (int ni = 0; ni < 4; ++ni)
#pragma unroll
        for (int j = 0; j < 4; ++j) {
          int row = mm * 16 + g * 4 + j, col = ni * 16 + c16;
          int off = (row * 256 + col * 4) ^ ((row & 7) << 4);
          *(float*)(eps + off) = acc[p * 2 + mm][ni][j];
        }
    asm volatile("s_waitcnt lgkmcnt(0)" ::: "memory");
#pragma unroll
    for (int it = 0; it < 8; ++it) {
      int c = it * 64 + lane;
      int row = c >> 4, ch = c & 15;
      int off = (row * 256 + ch * 16) ^ ((row & 7) << 4);
      float4 v = *(const float4*)(eps + off);
      size_t gr = (size_t)(m0 + wr * 64 + p * 32 + row) * 512 + n0 +
                  wc * 64 + ch * 4;
      float4 x = *(const float4*)(Xres + gr);
      v.x += x.x;
      v.y += x.y;
      v.z += x.z;
      v.w += x.w;
      *(float4*)(out + gr) = v;
    }
    asm volatile("s_waitcnt lgkmcnt(0)" ::: "memory");
  }
#undef OSTAGE
#undef OCOMPUTE
}

// ---------------------------------------------------------------------------
// Fused attention. Block = (b, h, 64 q-rows), 256 thr = 4 waves, 64 KB LDS.
//   [0,32768)     Ksm [256t][64d] swz -> P overlay [64q][256k] swz
//                 (wave-private rows; O re-tile reuses own-wave P rows)
//   [32768,65536) Vsm [64d][256t] swz
// K/V staged via global_load_lds with PRE-SWIZZLED global source (linear LDS
// dest; inverse permutation is the same XOR). Q loaded direct to registers.
// Q comes pre-scaled by temp[h]*log2e -> softmax is exp2, 1/sum deferred.
// ---------------------------------------------------------------------------
__global__ __launch_bounds__(256) void attn_fused(
    const bf16* __restrict__ Qn, const bf16* __restrict__ Kn,
    const bf16* __restrict__ Vt, bf16* __restrict__ O) {
  __shared__ __align__(16) char smem[65536];

  const int tid = threadIdx.x;
  const int w = tid >> 6, lane = tid & 63;
  const int g = lane >> 4, c16 = lane & 15;
  // XCD swizzle: 4096 = 8 XCDs x 512; blocks sharing (b,h) -> same XCD L2.
  const int lg = (blockIdx.x & 7) * 512 + (blockIdx.x >> 3);
  const int nt = lg & 63, h = (lg >> 6) & 7, b = lg >> 9;
  const int n0 = nt * 64;

  // ---- async stage K, V via gload_lds (pre-swizzled global source)
  {
    const bf16* Ksrc = Kn + ((size_t)b * 256) * 512 + h * 64;
    const bf16* Vsrc = Vt + (size_t)((b * 8 + h) * 64) * 256;
#pragma unroll
    for (int it = 0; it < 8; ++it) {
      int base = it * 256 + w * 64;  // wave-uniform chunk base
      int c = base + lane;
      int t = c >> 3, dk = (c & 7) ^ (t & 7);
      gload_lds16(Ksrc + (size_t)t * 512 + dk * 8, smem + base * 16);
      int d = c >> 5, tc = (c & 31) ^ (d & 7);
      gload_lds16(Vsrc + (size_t)d * 256 + tc * 8, smem + 32768 + base * 16);
    }
  }
  // ---- Q fragments direct to registers (no LDS round-trip)
  const int q = w * 16 + c16;  // this lane's q row (0..63)
  const bf16* Qsrc = Qn + ((size_t)b * 4096 + n0) * 512 + h * 64;
  bf16x8 qf[2];
  qf[0] = *(const bf16x8*)(Qsrc + (size_t)q * 512 + g * 8);
  qf[1] = *(const bf16x8*)(Qsrc + (size_t)q * 512 + 32 + g * 8);
  __syncthreads();  // drains gload_lds (vmcnt) + barrier

  // ---- S^T = mfma(K, Q^T): lane holds P[q][k], k = mi*16 + g*4 + j
  f32x4 sacc[16] = {};
#pragma unroll
  for (int mi = 0; mi < 16; ++mi) {
#pragma unroll
    for (int s = 0; s < 2; ++s) {
      int t = mi * 16 + c16;
      int off = (t * 128 + s * 64 + g * 16) ^ ((t & 7) << 4);
      bf16x8 kf = *(const bf16x8*)(smem + off);
      sacc[mi] = __builtin_amdgcn_mfma_f32_16x16x32_bf16(kf, qf[s], sacc[mi],
                                                         0, 0, 0);
    }
  }

  // ---- softmax over k (scores already include temp*log2e via Q scaling)
  float mx4[4] = {-1e30f, -1e30f, -1e30f, -1e30f};
#pragma unroll
  for (int mi = 0; mi < 16; ++mi)
#pragma unroll
    for (int j = 0; j < 4; ++j) mx4[j] = fmaxf(mx4[j], sacc[mi][j]);
  float mx = fmaxf(fmaxf(mx4[0], mx4[1]), fmaxf(mx4[2], mx4[3]));
  mx = fmaxf(mx, __shfl_xor(mx, 16, 64));
  mx = fmaxf(mx, __shfl_xor(mx, 32, 64));
  float sm4[4] = {0.f, 0.f, 0.f, 0.f};
#pragma unroll
  for (int mi = 0; mi < 16; ++mi)
#pragma unroll
    for (int j = 0; j < 4; ++j) {
      float p = EXP2(sacc[mi][j] - mx);
      sacc[mi][j] = p;
      sm4[j] += p;
    }
  float sum = (sm4[0] + sm4[1]) + (sm4[2] + sm4[3]);
  sum += __shfl_xor(sum, 16, 64);
  sum += __shfl_xor(sum, 32, 64);
  float inv = 1.0f / sum;

  __syncthreads();  // all K reads done; Ksm region now dead

  // ---- P[q][k] -> LDS overlay at base 0 (bf16, swizzled, UNnormalized).
  // P rows are wave-private (q = w*16 + c16) -> no barrier before PV.
#pragma unroll
  for (int mi = 0; mi < 16; ++mi) {
    uint2 v;
    v.x = pack2(sacc[mi][0], sacc[mi][1]);
    v.y = pack2(sacc[mi][2], sacc[mi][3]);
    int off = (q * 512 + mi * 32 + g * 8) ^ ((q & 7) << 4);
    *(uint2*)(smem + off) = v;
  }

  // ---- O = P @ V  (DS ops in-order per wave; own rows only)
  f32x4 oacc[4] = {};
#pragma unroll
  for (int ks = 0; ks < 8; ++ks) {
    int offa = (q * 512 + ks * 64 + g * 16) ^ ((q & 7) << 4);
    bf16x8 pa = *(const bf16x8*)(smem + offa);
#pragma unroll
    for (int ni = 0; ni < 4; ++ni) {
      int d = ni * 16 + c16;
      int offb = 32768 + ((d * 512 + ks * 64 + g * 16) ^ ((d & 7) << 4));
      bf16x8 vb = *(const bf16x8*)(smem + offb);
      oacc[ni] = __builtin_amdgcn_mfma_f32_16x16x32_bf16(pa, vb, oacc[ni],
                                                         0, 0, 0);
    }
  }

  // ---- normalize (deferred 1/sum) + O re-tile in own wave's dead P rows
  {
    char* ox = smem + w * 8192;  // wave w's P rows = [w*8192, w*8192+8K)
#pragma unroll
    for (int ni = 0; ni < 4; ++ni)
#pragma unroll
      for (int j = 0; j < 4; ++j) {
        int row = g * 4 + j, col = ni * 16 + c16;
        int off = (row * 128 + col * 2) ^ ((row & 7) << 4);
        *(bf16*)(ox + off) = (bf16)(oacc[ni][j] * inv);
      }
    asm volatile("s_waitcnt lgkmcnt(0)" ::: "memory");
#pragma unroll
    for (int it = 0; it < 2; ++it) {
      int c = it * 64 + lane;
      int row = c >> 3, ch = c & 7;
      int off = (row * 128 + ch * 16) ^ ((row & 7) << 4);
      bf16x8 v = *(const bf16x8*)(ox + off);
      *(bf16x8*)(O + ((size_t)b * 4096 + n0 + w * 16 + row) * 512 + h * 64 +
                 ch * 8) = v;
    }
  }
}

// ---------------------------------------------------------------------------
extern "C" void kernel_launch(void* const* d_in, const int* in_sizes, int n_in,
                              void* d_out, int out_size, void* d_ws,
                              size_t ws_size, hipStream_t stream) {
  const float* X = (const float*)d_in[0];
  const float* S = (const float*)d_in[1];
  const float* Wq = (const float*)d_in[2];
  const float* Wk = (const float*)d_in[3];
  const float* Wv = (const float*)d_in[4];
  const float* Wo = (const float*)d_in[5];
  const float* temp = (const float*)d_in[6];
  float* out = (float*)d_out;

  char* ws = (char*)d_ws;
  bf16* Qws = (bf16*)ws;                      // 32768*512*2 = 33,554,432 B
  bf16* Kws = (bf16*)(ws + 33554432);         //  2048*512*2 =  2,097,152 B
  bf16* Vtws = (bf16*)(ws + 35651584);        //  8*8*64*256*2 = 2,097,152 B
  bf16* Wqb = (bf16*)(ws + 37748736);         //  512*512*2 = 524,288 B each
  bf16* Wkb = (bf16*)(ws + 38273024);
  bf16* Wvb = (bf16*)(ws + 38797312);
  bf16* Wob = (bf16*)(ws + 39321600);

  // Xb/Sb scratch inside d_out (67.1 MB f32): dead before out_gemm writes.
  bf16* Xb = (bf16*)d_out;                      // 33,554,432 B
  bf16* Sb = (bf16*)((char*)d_out + 33554432);  //  2,097,152 B

  cvt_all<<<dim3(9216), dim3(256), 0, stream>>>(X, S, Wq, Wk, Wv, Wo, Xb, Sb,
                                                Wqb, Wkb, Wvb, Wob);
  proj_all<<<dim3(1152), dim3(256), 0, stream>>>(Xb, Sb, Wqb, Wkb, Wvb, temp,
                                                 Qws, Kws, Vtws);
  attn_fused<<<dim3(4096), dim3(256), 0, stream>>>(Qws, Kws, Vtws, Qws);
  out_gemm<<<dim3(1024), dim3(256), 0, stream>>>(Qws, Wob, X, out);
}